// Round 8
// baseline (453.468 us; speedup 1.0000x reference)
//
#include <hip/hip_runtime.h>
#include <hip/hip_bf16.h>

// Transformer block for MI355X. Round 16: attention 4-waves/SIMD via WIDE block.
//  - r11/r12/r13 showed the scheduler never co-resides two 512-thread attn
//    blocks on a CU. Loophole: ONE 1024-thread block = 16 waves = 4/SIMD,
//    guaranteed. Each thread-half (tid>>9) runs the proven r15 attn body for
//    bh = blockIdx.y*2 + half, with its own LDS set (137KB total). Both
//    halves share qt per pass -> identical iter counts -> barriers align.
//    Grid (8,16) = 128 blocks x 34 balanced k-iters; latency-bound so using
//    half the CUs at 2x waves/SIMD is a net win.
//  - gemm256 (qkv/fc1), gemm128 (proj/fc2-splitK), rmsnorm, wprep, red2
//    unchanged from r15.
// All symbols _r16 (fresh build).

typedef __hip_bfloat16 bf16;
typedef __attribute__((ext_vector_type(8))) short short8;   // 8 bf16 = 4 VGPRs
typedef __attribute__((ext_vector_type(4))) float floatx4;  // MFMA C/D frag

__device__ __forceinline__ float bits2f(unsigned short u) {
  union { unsigned int i; float f; } c; c.i = ((unsigned int)u) << 16; return c.f;
}
__device__ __forceinline__ unsigned short f2bits(float f) {
  bf16 b = __float2bfloat16(f);
  union { bf16 b; unsigned short u; } c; c.b = b; return c.u;
}

__device__ __forceinline__ void gld_lds16(const unsigned short* g, unsigned short* l) {
  __builtin_amdgcn_global_load_lds(
      (const __attribute__((address_space(1))) void*)g,
      (__attribute__((address_space(3))) void*)l, 16, 0, 0);
}

// ---------------- RMSNorm: f32 in, f32 gamma, bf16 out ----------------
__global__ __launch_bounds__(256) void rmsnorm_r16(const float* __restrict__ x,
                                                   const float* __restrict__ g,
                                                   unsigned short* __restrict__ out)
{
  const int row = blockIdx.x, tid = threadIdx.x;
  const size_t rb = (size_t)row * 1024;
  float4 xv = *(const float4*)(x + rb + tid * 4);
  float v[4] = {xv.x, xv.y, xv.z, xv.w};
  float s = v[0]*v[0] + v[1]*v[1] + v[2]*v[2] + v[3]*v[3];
  #pragma unroll
  for (int off = 32; off > 0; off >>= 1) s += __shfl_down(s, off, 64);
  __shared__ float part[4];
  if ((tid & 63) == 0) part[tid >> 6] = s;
  __syncthreads();
  const float tot = part[0] + part[1] + part[2] + part[3];
  const float sc = rsqrtf(tot * (1.0f / 1024.0f) + 1.1920929e-07f);
  float4 gv = *(const float4*)(g + tid * 4);
  ushort4 o4 = { f2bits(v[0] * sc * gv.x), f2bits(v[1] * sc * gv.y),
                 f2bits(v[2] * sc * gv.z), f2bits(v[3] * sc * gv.w) };
  *(ushort4*)(out + rb + tid * 4) = o4;
}

// ---------------- Weight prep: W f32 [K,N] -> WT bf16 [N,K] ----------------
__global__ __launch_bounds__(256) void wprep_r16(const float* __restrict__ in,
                                                 unsigned short* __restrict__ out,
                                                 int K, int N)
{
  __shared__ unsigned short tile[32][33];
  const int tid = threadIdx.x;
  const int k0 = blockIdx.y * 32, n0 = blockIdx.x * 32;
  const int tr = tid >> 3, tc4 = (tid & 7) * 4;
  float4 v = *(const float4*)(in + (size_t)(k0 + tr) * N + n0 + tc4);
  tile[tr][tc4 + 0] = f2bits(v.x);
  tile[tr][tc4 + 1] = f2bits(v.y);
  tile[tr][tc4 + 2] = f2bits(v.z);
  tile[tr][tc4 + 3] = f2bits(v.w);
  __syncthreads();
  ushort4 o = { tile[tc4 + 0][tr], tile[tc4 + 1][tr],
                tile[tc4 + 2][tr], tile[tc4 + 3][tr] };
  *(ushort4*)(out + (size_t)(n0 + tr) * K + k0 + tc4) = o;
}

// ---------------- 128x128 MFMA GEMM (proj / fc2-splitK) ----------------
// EPI: 0=bf16  1=f32+resid  2=gelu->bf16  3=f32+resid  4=f32 partial (split-K)
template<int EPI>
__global__ __launch_bounds__(256) void gemm128_r16(
    const unsigned short* __restrict__ A,
    const unsigned short* __restrict__ BT,
    const float* __restrict__ bias,
    const float* __restrict__ resid,
    void* __restrict__ Cout,
    int M, int N, int K, int Klen)
{
  __shared__ __align__(16) unsigned short As[2][128 * 32];
  __shared__ __align__(16) unsigned short Bs[2][128 * 32];
  const int tid = threadIdx.x;
  const int lane = tid & 63;
  const int wv = tid >> 6;
  const int m0 = blockIdx.y * 128, n0 = blockIdx.x * 128;
  const int wm = (wv >> 1) * 64, wn = (wv & 1) * 64;
  const int kbase = blockIdx.z * Klen;

  const int s0 = tid, s1 = tid + 256;
  const int r0 = s0 >> 2, kq0 = (s0 & 3) ^ ((r0 >> 1) & 3);
  const int r1 = s1 >> 2, kq1 = (s1 & 3) ^ ((r1 >> 1) & 3);
  const unsigned short* Ab = A  + (size_t)m0 * K;
  const unsigned short* Bb = BT + (size_t)n0 * K;
  const size_t ga0 = (size_t)r0 * K + kq0 * 8 + kbase;
  const size_t ga1 = (size_t)r1 * K + kq1 * 8 + kbase;

  floatx4 acc[4][4];
  #pragma unroll
  for (int i = 0; i < 4; ++i)
    #pragma unroll
    for (int j = 0; j < 4; ++j)
      acc[i][j] = (floatx4){0.f, 0.f, 0.f, 0.f};

  int aoff[4], boff[4];
  #pragma unroll
  for (int i = 0; i < 4; ++i) {
    int ra = wm + i * 16 + (lane & 15);
    aoff[i] = (ra * 4 + ((lane >> 4) ^ ((ra >> 1) & 3))) * 8;
    int rb = wn + i * 16 + (lane & 15);
    boff[i] = (rb * 4 + ((lane >> 4) ^ ((rb >> 1) & 3))) * 8;
  }

  gld_lds16(Ab + ga0, As[0] + s0 * 8);
  gld_lds16(Ab + ga1, As[0] + s1 * 8);
  gld_lds16(Bb + ga0, Bs[0] + s0 * 8);
  gld_lds16(Bb + ga1, Bs[0] + s1 * 8);
  __syncthreads();

  const int nsteps = Klen >> 5;
  for (int t = 0; t < nsteps; ++t) {
    const int cur = t & 1;
    if (t + 1 < nsteps) {
      const size_t ko = (size_t)(t + 1) * 32;
      gld_lds16(Ab + ga0 + ko, As[cur ^ 1] + s0 * 8);
      gld_lds16(Ab + ga1 + ko, As[cur ^ 1] + s1 * 8);
      gld_lds16(Bb + ga0 + ko, Bs[cur ^ 1] + s0 * 8);
      gld_lds16(Bb + ga1 + ko, Bs[cur ^ 1] + s1 * 8);
    }

    short8 af[4], bfr[4];
    #pragma unroll
    for (int i = 0; i < 4; ++i) {
      af[i]  = *(const short8*)(As[cur] + aoff[i]);
      bfr[i] = *(const short8*)(Bs[cur] + boff[i]);
    }
    #pragma unroll
    for (int i = 0; i < 4; ++i)
      #pragma unroll
      for (int j = 0; j < 4; ++j)
        acc[i][j] = __builtin_amdgcn_mfma_f32_16x16x32_bf16(af[i], bfr[j], acc[i][j], 0, 0, 0);

    __syncthreads();
  }

  float* Cp32 = (float*)Cout;
  if constexpr (EPI == 4) Cp32 += (size_t)blockIdx.z * ((size_t)M * N);

  #pragma unroll
  for (int i = 0; i < 4; ++i) {
    #pragma unroll
    for (int j = 0; j < 4; ++j) {
      const int rbase = m0 + wm + i * 16 + (lane >> 4) * 4;
      const int c = n0 + wn + j * 16 + (lane & 15);
      float bia = 0.0f;
      if constexpr (EPI != 4) bia = bias[c];
      #pragma unroll
      for (int r = 0; r < 4; ++r) {
        float v = acc[i][j][r] + bia;
        const size_t idx = (size_t)(rbase + r) * N + c;
        if constexpr (EPI == 0) {
          ((unsigned short*)Cout)[idx] = f2bits(v);
        } else if constexpr (EPI == 1) {
          ((float*)Cout)[idx] = v + resid[idx];
        } else if constexpr (EPI == 2) {
          v = 0.5f * v * (1.0f + erff(v * 0.70710678118654752f));
          ((unsigned short*)Cout)[idx] = f2bits(v);
        } else if constexpr (EPI == 3) {
          ((float*)Cout)[idx] = v + resid[idx];
        } else {
          Cp32[idx] = v;
        }
      }
    }
  }
}

// ---------------- 256x256 MFMA GEMM (qkv / fc1): 4-ring + counted vmcnt ----------------
template<int EPI>
__global__ __launch_bounds__(512) void gemm256_r16(
    const unsigned short* __restrict__ A,
    const unsigned short* __restrict__ BT,
    const float* __restrict__ bias,
    void* __restrict__ Cout,
    int M, int N, int K)
{
  __shared__ __align__(16) unsigned short As[4][256 * 32];
  __shared__ __align__(16) unsigned short Bs[4][256 * 32];
  const int tid = threadIdx.x;
  const int lane = tid & 63, wv = tid >> 6;
  const int quad = lane >> 4, l15 = lane & 15;
  const int m0 = blockIdx.y * 256, n0 = blockIdx.x * 256;
  const int wm = (wv >> 2) * 128, wn = (wv & 3) * 64;

  const int s0 = tid, s1 = tid + 512;
  const int r0 = s0 >> 2, kq0 = (s0 & 3) ^ ((r0 >> 1) & 3);
  const int r1 = s1 >> 2, kq1 = (s1 & 3) ^ ((r1 >> 1) & 3);
  const unsigned short* Ab = A  + (size_t)m0 * K;
  const unsigned short* Bb = BT + (size_t)n0 * K;
  const size_t ga0 = (size_t)r0 * K + kq0 * 8;
  const size_t ga1 = (size_t)r1 * K + kq1 * 8;

  floatx4 acc[8][4];
  #pragma unroll
  for (int i = 0; i < 8; ++i)
    #pragma unroll
    for (int j = 0; j < 4; ++j)
      acc[i][j] = (floatx4){0.f, 0.f, 0.f, 0.f};

  int aoff[8], boff[4];
  #pragma unroll
  for (int i = 0; i < 8; ++i) {
    int ra = wm + i * 16 + l15;
    aoff[i] = (ra * 4 + (quad ^ ((ra >> 1) & 3))) * 8;
  }
  #pragma unroll
  for (int j = 0; j < 4; ++j) {
    int rb = wn + j * 16 + l15;
    boff[j] = (rb * 4 + (quad ^ ((rb >> 1) & 3))) * 8;
  }

  #define STG_R16(t) { const size_t ko = (size_t)(t) * 32; const int bb = (t) & 3; \
    gld_lds16(Ab + ga0 + ko, As[bb] + s0 * 8); \
    gld_lds16(Ab + ga1 + ko, As[bb] + s1 * 8); \
    gld_lds16(Bb + ga0 + ko, Bs[bb] + s0 * 8); \
    gld_lds16(Bb + ga1 + ko, Bs[bb] + s1 * 8); }

  STG_R16(0);
  STG_R16(1);

  const int nsteps = K >> 5;
  for (int t = 0; t < nsteps; ++t) {
    const int cur = t & 3;
    if (t + 2 < nsteps) {
      STG_R16(t + 2);
      asm volatile("s_waitcnt vmcnt(8)" ::: "memory");
    } else if (t + 1 < nsteps) {
      asm volatile("s_waitcnt vmcnt(4)" ::: "memory");
    } else {
      asm volatile("s_waitcnt vmcnt(0)" ::: "memory");
    }
    __builtin_amdgcn_s_barrier();
    asm volatile("" ::: "memory");

    short8 bfr[4];
    #pragma unroll
    for (int j = 0; j < 4; ++j)
      bfr[j] = *(const short8*)(Bs[cur] + boff[j]);
    #pragma unroll
    for (int ih = 0; ih < 2; ++ih) {
      short8 af[4];
      #pragma unroll
      for (int k = 0; k < 4; ++k)
        af[k] = *(const short8*)(As[cur] + aoff[ih * 4 + k]);
      #pragma unroll
      for (int k = 0; k < 4; ++k)
        #pragma unroll
        for (int j = 0; j < 4; ++j)
          acc[ih * 4 + k][j] = __builtin_amdgcn_mfma_f32_16x16x32_bf16(af[k], bfr[j], acc[ih * 4 + k][j], 0, 0, 0);
    }
  }
  #undef STG_R16

  #pragma unroll
  for (int i = 0; i < 8; ++i) {
    #pragma unroll
    for (int j = 0; j < 4; ++j) {
      const int rbase = m0 + wm + i * 16 + quad * 4;
      const int c = n0 + wn + j * 16 + l15;
      const float bia = bias[c];
      #pragma unroll
      for (int r = 0; r < 4; ++r) {
        float v = acc[i][j][r] + bia;
        const size_t idx = (size_t)(rbase + r) * N + c;
        if constexpr (EPI == 2) {
          v = 0.5f * v * (1.0f + erff(v * 0.70710678118654752f));
        }
        ((unsigned short*)Cout)[idx] = f2bits(v);
      }
    }
  }
}

// ---------------- split-K reduce: out = P0 + P1 + resid + bias ----------------
__global__ __launch_bounds__(256) void red2_r16(const float* __restrict__ P,
                                                const float* __restrict__ resid,
                                                const float* __restrict__ bias,
                                                float* __restrict__ out)
{
  const size_t i = ((size_t)blockIdx.x * 256 + threadIdx.x) * 4;
  const int col = (int)(i & 1023);
  float4 p0 = *(const float4*)(P + i);
  float4 p1 = *(const float4*)(P + ((size_t)4096 * 1024) + i);
  float4 xr = *(const float4*)(resid + i);
  float4 b  = *(const float4*)(bias + col);
  float4 o  = { p0.x + p1.x + xr.x + b.x, p0.y + p1.y + xr.y + b.y,
                p0.z + p1.z + xr.z + b.z, p0.w + p1.w + xr.w + b.w };
  *(float4*)(out + i) = o;
}

// ---------------- MFMA flash attention (r16: wide block, 2 heads per block) ----------------
// qkv: [B*T, 3072] bf16. o: [B*T,1024] bf16. Grid dim3(8,16), 1024 threads.
// half = tid>>9 processes bh = blockIdx.y*2 + half with its own LDS set.
// Both halves share qt per pass -> identical barrier counts. 16 waves/CU.
__global__ __launch_bounds__(1024) void attn_r16(const unsigned short* __restrict__ qkv,
                                                 unsigned short* __restrict__ o)
{
  __shared__ __align__(16) unsigned short Qs[2][128 * 64];     // per-half, swizzled
  __shared__ __align__(16) unsigned short Ks[2][2][64 * 64];   // [half][dbuf]
  __shared__ __align__(16) unsigned short VT[2][2][64 * 72];   // [half][dbuf]
  __shared__ __align__(16) unsigned short Ps[2][128 * 72];
  __shared__ __align__(16) float stat_s[2][128];

  const int tid = threadIdx.x;
  const int half = tid >> 9;
  const int t = tid & 511;
  const int lane = t & 63, wv = t >> 6;
  const int quad = lane >> 4, l15 = lane & 15;
  const int qt0 = blockIdx.x;
  const int bh = blockIdx.y * 2 + half;
  const int b = bh >> 4, h = bh & 15;
  const size_t base = (size_t)b * 2048 * 3072;
  const int qcol = h * 64, kcol = 1024 + h * 64, vcol = 2048 + h * 64;

  unsigned short* Qh = Qs[half];
  unsigned short* Ph = Ps[half];
  float* sth = stat_s[half];

  const int sr = t >> 3, scp = t & 7, sc = scp ^ (sr & 7);
  const unsigned short* kgp = qkv + base + (size_t)sr * 3072 + kcol + sc * 8;
  const int vp = t & 31, vdc = t >> 5;
  const unsigned short* vgp = qkv + base + (size_t)(2 * vp) * 3072 + vcol + vdc * 4;

  for (int pass = 0; pass < 2; ++pass) {
    const int qt = pass ? qt0 : 15 - qt0;
    const int q0 = qt * 128;
    const int nkt = 2 * qt + 2;

    __syncthreads();

    #pragma unroll
    for (int p = 0; p < 2; ++p) {
      int s = t + 512 * p;
      int r = s >> 3, cp = s & 7, c = cp ^ (r & 7);
      gld_lds16(qkv + base + (size_t)(q0 + r) * 3072 + qcol + c * 8, Qh + s * 8);
    }
    gld_lds16(kgp, Ks[half][0] + t * 8);
    {
      uint2 u0 = *(const uint2*)vgp;
      uint2 u1 = *(const uint2*)(vgp + 3072);
      unsigned short* dst = VT[half][0] + (size_t)(vdc * 4) * 72 + 2 * vp;
      *(unsigned int*)(dst + 0 * 72) = (u0.x & 0xffffu) | (u1.x << 16);
      *(unsigned int*)(dst + 1 * 72) = (u0.x >> 16)     | (u1.x & 0xffff0000u);
      *(unsigned int*)(dst + 2 * 72) = (u0.y & 0xffffu) | (u1.y << 16);
      *(unsigned int*)(dst + 3 * 72) = (u0.y >> 16)     | (u1.y & 0xffff0000u);
    }
    __syncthreads();

    short8 qa[2];
    #pragma unroll
    for (int ks = 0; ks < 2; ++ks) {
      int ra = wv * 16 + l15;
      int cp = (ks * 4 + quad) ^ (ra & 7);
      qa[ks] = *(const short8*)(Qh + (ra * 8 + cp) * 8);
    }

    floatx4 oacc[4];
    #pragma unroll
    for (int dt = 0; dt < 4; ++dt) oacc[dt] = (floatx4){0.f, 0.f, 0.f, 0.f};
    float m_i[4], l_i[4];
    #pragma unroll
    for (int r = 0; r < 4; ++r) { m_i[r] = -3.0e38f; l_i[r] = 0.0f; }

    for (int kt = 0; kt < nkt; ++kt) {
      const int cur = kt & 1;
      const bool pf = (kt + 1 < nkt);
      uint2 u0, u1;
      if (pf) {
        const size_t koff = (size_t)(kt + 1) * 64 * 3072;
        gld_lds16(kgp + koff, Ks[half][cur ^ 1] + t * 8);
        u0 = *(const uint2*)(vgp + koff);
        u1 = *(const uint2*)(vgp + koff + 3072);
      }

      short8 kb[4][2];
      #pragma unroll
      for (int j = 0; j < 4; ++j)
        #pragma unroll
        for (int ks = 0; ks < 2; ++ks) {
          int rb = j * 16 + l15;
          int cp = (ks * 4 + quad) ^ (rb & 7);
          kb[j][ks] = *(const short8*)(Ks[half][cur] + (rb * 8 + cp) * 8);
        }
      floatx4 s_[4];
      #pragma unroll
      for (int j = 0; j < 4; ++j) s_[j] = (floatx4){0.f, 0.f, 0.f, 0.f};
      #pragma unroll
      for (int j = 0; j < 4; ++j)
        #pragma unroll
        for (int ks = 0; ks < 2; ++ks)
          s_[j] = __builtin_amdgcn_mfma_f32_16x16x32_bf16(qa[ks], kb[j][ks], s_[j], 0, 0, 0);

      const int k0 = kt * 64;
      const int rowmin = q0 + wv * 16;
      const int rowb = rowmin + quad * 4;
      if (k0 + 63 > rowmin) {
        #pragma unroll
        for (int j = 0; j < 4; ++j) {
          const int col = k0 + j * 16 + l15;
          #pragma unroll
          for (int r = 0; r < 4; ++r)
            if (col > rowb + r) s_[j][r] = -3.0e38f;
        }
      }
      float fm[4], al[4], rs[4];
      #pragma unroll
      for (int r = 0; r < 4; ++r)
        fm[r] = fmaxf(fmaxf(s_[0][r], s_[1][r]), fmaxf(s_[2][r], s_[3][r]));
      #pragma unroll
      for (int msk = 1; msk < 16; msk <<= 1)
        #pragma unroll
        for (int r = 0; r < 4; ++r)
          fm[r] = fmaxf(fm[r], __shfl_xor(fm[r], msk, 64));
      #pragma unroll
      for (int r = 0; r < 4; ++r) {
        const float mn = fmaxf(m_i[r], fm[r]);
        al[r] = __expf(m_i[r] - mn);
        m_i[r] = mn;
      }
      #pragma unroll
      for (int j = 0; j < 4; ++j)
        #pragma unroll
        for (int r = 0; r < 4; ++r)
          s_[j][r] = __expf(s_[j][r] - m_i[r]);
      #pragma unroll
      for (int r = 0; r < 4; ++r)
        rs[r] = (s_[0][r] + s_[1][r]) + (s_[2][r] + s_[3][r]);
      #pragma unroll
      for (int msk = 1; msk < 16; msk <<= 1)
        #pragma unroll
        for (int r = 0; r < 4; ++r)
          rs[r] += __shfl_xor(rs[r], msk, 64);
      #pragma unroll
      for (int r = 0; r < 4; ++r)
        l_i[r] = l_i[r] * al[r] + rs[r];
      if (l15 == 0) {
        float4 a4 = { al[0], al[1], al[2], al[3] };
        *(float4*)(sth + wv * 16 + quad * 4) = a4;
      }
      #pragma unroll
      for (int j = 0; j < 4; ++j)
        #pragma unroll
        for (int r = 0; r < 4; ++r)
          Ph[(size_t)(wv * 16 + quad * 4 + r) * 72 + j * 16 + l15] = f2bits(s_[j][r]);

      const float alq = sth[wv * 16 + l15];
      #pragma unroll
      for (int dt = 0; dt < 4; ++dt)
        #pragma unroll
        for (int r = 0; r < 4; ++r)
          oacc[dt][r] *= alq;

      short8 va[4][2], pb[2];
      #pragma unroll
      for (int dt = 0; dt < 4; ++dt)
        #pragma unroll
        for (int ks = 0; ks < 2; ++ks)
          va[dt][ks] = *(const short8*)(VT[half][cur] + (size_t)(dt * 16 + l15) * 72 + ks * 32 + quad * 8);
      #pragma unroll
      for (int ks = 0; ks < 2; ++ks)
        pb[ks] = *(const short8*)(Ph + (size_t)(wv * 16 + l15) * 72 + ks * 32 + quad * 8);
      #pragma unroll
      for (int dt = 0; dt < 4; ++dt)
        #pragma unroll
        for (int ks = 0; ks < 2; ++ks)
          oacc[dt] = __builtin_amdgcn_mfma_f32_16x16x32_bf16(va[dt][ks], pb[ks], oacc[dt], 0, 0, 0);

      if (pf) {
        unsigned short* dst = VT[half][cur ^ 1] + (size_t)(vdc * 4) * 72 + 2 * vp;
        *(unsigned int*)(dst + 0 * 72) = (u0.x & 0xffffu) | (u1.x << 16);
        *(unsigned int*)(dst + 1 * 72) = (u0.x >> 16)     | (u1.x & 0xffff0000u);
        *(unsigned int*)(dst + 2 * 72) = (u0.y & 0xffffu) | (u1.y << 16);
        *(unsigned int*)(dst + 3 * 72) = (u0.y >> 16)     | (u1.y & 0xffff0000u);
      }
      __syncthreads();
    }

    if (l15 == 0) {
      float4 l4 = { l_i[0], l_i[1], l_i[2], l_i[3] };
      *(float4*)(sth + wv * 16 + quad * 4) = l4;
    }
    const float linv = 0.03125f / sth[wv * 16 + l15];
    const size_t row = (size_t)b * 2048 + q0 + wv * 16 + l15;
    #pragma unroll
    for (int dt = 0; dt < 4; ++dt) {
      const int col = h * 64 + dt * 16 + quad * 4;
      ushort4 o4 = { f2bits(oacc[dt][0] * linv), f2bits(oacc[dt][1] * linv),
                     f2bits(oacc[dt][2] * linv), f2bits(oacc[dt][3] * linv) };
      *(ushort4*)(o + row * 1024 + col) = o4;
    }
  }
}

extern "C" void kernel_launch(void* const* d_in, const int* in_sizes, int n_in,
                              void* d_out, int out_size, void* d_ws, size_t ws_size,
                              hipStream_t stream)
{
  (void)in_sizes; (void)n_in; (void)out_size; (void)ws_size;
  const float* x      = (const float*)d_in[0];
  const float* w_attn = (const float*)d_in[1];
  const float* b_attn = (const float*)d_in[2];
  const float* w_proj = (const float*)d_in[3];
  const float* b_proj = (const float*)d_in[4];
  const float* w_fc1  = (const float*)d_in[5];
  const float* b_fc1  = (const float*)d_in[6];
  const float* w_fc2  = (const float*)d_in[7];
  const float* b_fc2  = (const float*)d_in[8];
  const float* g1     = (const float*)d_in[9];
  const float* g2     = (const float*)d_in[10];
  float* out = (float*)d_out;

  // ws layout (88 MB): h/ov bf16 @0 (8MB), qkv bf16 @8MB (24MB, h2 reuses 8..16MB),
  //                    x1 f32 @32MB (16MB), h3 bf16 @48MB (32MB), WT scratch @80MB (8MB)
  // fc2 split-K partials (2 x 16MB f32) reuse 0..32MB (h/h2/qkv/ov all dead there).
  char* ws = (char*)d_ws;
  unsigned short* h   = (unsigned short*)(ws);
  unsigned short* qkv = (unsigned short*)(ws + ((size_t)8  << 20));
  unsigned short* ov  = (unsigned short*)(ws);                       // reuse h
  float*          x1  = (float*)         (ws + ((size_t)32 << 20));
  unsigned short* h2  = (unsigned short*)(ws + ((size_t)8  << 20));  // reuse qkv
  unsigned short* h3  = (unsigned short*)(ws + ((size_t)48 << 20));
  unsigned short* WT  = (unsigned short*)(ws + ((size_t)80 << 20));
  float*          P   = (float*)(ws);                                // fc2 split-K partials

  const int M = 4096;

  rmsnorm_r16<<<M, 256, 0, stream>>>(x, g1, h);
  wprep_r16<<<dim3(3072 / 32, 1024 / 32), 256, 0, stream>>>(w_attn, WT, 1024, 3072);
  gemm256_r16<0><<<dim3(3072 / 256, M / 256), 512, 0, stream>>>(h, WT, b_attn, qkv, M, 3072, 1024);
  attn_r16<<<dim3(8, 16), 1024, 0, stream>>>(qkv, ov);
  wprep_r16<<<dim3(1024 / 32, 1024 / 32), 256, 0, stream>>>(w_proj, WT, 1024, 1024);
  gemm128_r16<1><<<dim3(1024 / 128, M / 128), 256, 0, stream>>>(ov, WT, b_proj, x, x1, M, 1024, 1024, 1024);
  rmsnorm_r16<<<M, 256, 0, stream>>>(x1, g2, h2);
  wprep_r16<<<dim3(4096 / 32, 1024 / 32), 256, 0, stream>>>(w_fc1, WT, 1024, 4096);
  gemm256_r16<2><<<dim3(4096 / 256, M / 256), 512, 0, stream>>>(h2, WT, b_fc1, h3, M, 4096, 1024);
  wprep_r16<<<dim3(1024 / 32, 4096 / 32), 256, 0, stream>>>(w_fc2, WT, 4096, 1024);
  gemm128_r16<4><<<dim3(1024 / 128, M / 128, 2), 256, 0, stream>>>(h3, WT, nullptr, nullptr, P, M, 1024, 4096, 2048);
  red2_r16<<<4096, 256, 0, stream>>>(P, x1, b_fc2, out);
}

// Round 9
// 389.654 us; speedup vs baseline: 1.1638x; 1.1638x over previous
//
#include <hip/hip_runtime.h>
#include <hip/hip_bf16.h>

// Transformer block for MI355X. Round 17: attention counted-vmcnt pipeline.
//  - r16 post-mortem: wide block halved CU count for +18% overlap -> net loss.
//    TLP scaling weak => iter cost is the __syncthreads vmcnt(0) drain of
//    just-issued staging loads (T4 lesson: drain-0 == unpipelined).
//  - r17 attn: 2-iter prefetch depth. Ks[3] ring, V regs double-buffered
//    (loop unrolled x2, static reg sets), per-iter: issue K/V(t+2), compute,
//    s_waitcnt vmcnt(3) (K/V(t+1) landed, t+2 stays in flight ACROSS the
//    barrier), write VT, lgkmcnt(0), raw s_barrier. Tail drains once.
//  - gemm256 (qkv/fc1), gemm128 (proj/fc2-splitK), rmsnorm, wprep, red2
//    unchanged from r15 (total 379.4us baseline).
// All symbols _r17 (fresh build).

typedef __hip_bfloat16 bf16;
typedef __attribute__((ext_vector_type(8))) short short8;   // 8 bf16 = 4 VGPRs
typedef __attribute__((ext_vector_type(4))) float floatx4;  // MFMA C/D frag

__device__ __forceinline__ float bits2f(unsigned short u) {
  union { unsigned int i; float f; } c; c.i = ((unsigned int)u) << 16; return c.f;
}
__device__ __forceinline__ unsigned short f2bits(float f) {
  bf16 b = __float2bfloat16(f);
  union { bf16 b; unsigned short u; } c; c.b = b; return c.u;
}

__device__ __forceinline__ void gld_lds16(const unsigned short* g, unsigned short* l) {
  __builtin_amdgcn_global_load_lds(
      (const __attribute__((address_space(1))) void*)g,
      (__attribute__((address_space(3))) void*)l, 16, 0, 0);
}

// ---------------- RMSNorm: f32 in, f32 gamma, bf16 out ----------------
__global__ __launch_bounds__(256) void rmsnorm_r17(const float* __restrict__ x,
                                                   const float* __restrict__ g,
                                                   unsigned short* __restrict__ out)
{
  const int row = blockIdx.x, tid = threadIdx.x;
  const size_t rb = (size_t)row * 1024;
  float4 xv = *(const float4*)(x + rb + tid * 4);
  float v[4] = {xv.x, xv.y, xv.z, xv.w};
  float s = v[0]*v[0] + v[1]*v[1] + v[2]*v[2] + v[3]*v[3];
  #pragma unroll
  for (int off = 32; off > 0; off >>= 1) s += __shfl_down(s, off, 64);
  __shared__ float part[4];
  if ((tid & 63) == 0) part[tid >> 6] = s;
  __syncthreads();
  const float tot = part[0] + part[1] + part[2] + part[3];
  const float sc = rsqrtf(tot * (1.0f / 1024.0f) + 1.1920929e-07f);
  float4 gv = *(const float4*)(g + tid * 4);
  ushort4 o4 = { f2bits(v[0] * sc * gv.x), f2bits(v[1] * sc * gv.y),
                 f2bits(v[2] * sc * gv.z), f2bits(v[3] * sc * gv.w) };
  *(ushort4*)(out + rb + tid * 4) = o4;
}

// ---------------- Weight prep: W f32 [K,N] -> WT bf16 [N,K] ----------------
__global__ __launch_bounds__(256) void wprep_r17(const float* __restrict__ in,
                                                 unsigned short* __restrict__ out,
                                                 int K, int N)
{
  __shared__ unsigned short tile[32][33];
  const int tid = threadIdx.x;
  const int k0 = blockIdx.y * 32, n0 = blockIdx.x * 32;
  const int tr = tid >> 3, tc4 = (tid & 7) * 4;
  float4 v = *(const float4*)(in + (size_t)(k0 + tr) * N + n0 + tc4);
  tile[tr][tc4 + 0] = f2bits(v.x);
  tile[tr][tc4 + 1] = f2bits(v.y);
  tile[tr][tc4 + 2] = f2bits(v.z);
  tile[tr][tc4 + 3] = f2bits(v.w);
  __syncthreads();
  ushort4 o = { tile[tc4 + 0][tr], tile[tc4 + 1][tr],
                tile[tc4 + 2][tr], tile[tc4 + 3][tr] };
  *(ushort4*)(out + (size_t)(n0 + tr) * K + k0 + tc4) = o;
}

// ---------------- 128x128 MFMA GEMM (proj / fc2-splitK) ----------------
// EPI: 0=bf16  1=f32+resid  2=gelu->bf16  3=f32+resid  4=f32 partial (split-K)
template<int EPI>
__global__ __launch_bounds__(256) void gemm128_r17(
    const unsigned short* __restrict__ A,
    const unsigned short* __restrict__ BT,
    const float* __restrict__ bias,
    const float* __restrict__ resid,
    void* __restrict__ Cout,
    int M, int N, int K, int Klen)
{
  __shared__ __align__(16) unsigned short As[2][128 * 32];
  __shared__ __align__(16) unsigned short Bs[2][128 * 32];
  const int tid = threadIdx.x;
  const int lane = tid & 63;
  const int wv = tid >> 6;
  const int m0 = blockIdx.y * 128, n0 = blockIdx.x * 128;
  const int wm = (wv >> 1) * 64, wn = (wv & 1) * 64;
  const int kbase = blockIdx.z * Klen;

  const int s0 = tid, s1 = tid + 256;
  const int r0 = s0 >> 2, kq0 = (s0 & 3) ^ ((r0 >> 1) & 3);
  const int r1 = s1 >> 2, kq1 = (s1 & 3) ^ ((r1 >> 1) & 3);
  const unsigned short* Ab = A  + (size_t)m0 * K;
  const unsigned short* Bb = BT + (size_t)n0 * K;
  const size_t ga0 = (size_t)r0 * K + kq0 * 8 + kbase;
  const size_t ga1 = (size_t)r1 * K + kq1 * 8 + kbase;

  floatx4 acc[4][4];
  #pragma unroll
  for (int i = 0; i < 4; ++i)
    #pragma unroll
    for (int j = 0; j < 4; ++j)
      acc[i][j] = (floatx4){0.f, 0.f, 0.f, 0.f};

  int aoff[4], boff[4];
  #pragma unroll
  for (int i = 0; i < 4; ++i) {
    int ra = wm + i * 16 + (lane & 15);
    aoff[i] = (ra * 4 + ((lane >> 4) ^ ((ra >> 1) & 3))) * 8;
    int rb = wn + i * 16 + (lane & 15);
    boff[i] = (rb * 4 + ((lane >> 4) ^ ((rb >> 1) & 3))) * 8;
  }

  gld_lds16(Ab + ga0, As[0] + s0 * 8);
  gld_lds16(Ab + ga1, As[0] + s1 * 8);
  gld_lds16(Bb + ga0, Bs[0] + s0 * 8);
  gld_lds16(Bb + ga1, Bs[0] + s1 * 8);
  __syncthreads();

  const int nsteps = Klen >> 5;
  for (int t = 0; t < nsteps; ++t) {
    const int cur = t & 1;
    if (t + 1 < nsteps) {
      const size_t ko = (size_t)(t + 1) * 32;
      gld_lds16(Ab + ga0 + ko, As[cur ^ 1] + s0 * 8);
      gld_lds16(Ab + ga1 + ko, As[cur ^ 1] + s1 * 8);
      gld_lds16(Bb + ga0 + ko, Bs[cur ^ 1] + s0 * 8);
      gld_lds16(Bb + ga1 + ko, Bs[cur ^ 1] + s1 * 8);
    }

    short8 af[4], bfr[4];
    #pragma unroll
    for (int i = 0; i < 4; ++i) {
      af[i]  = *(const short8*)(As[cur] + aoff[i]);
      bfr[i] = *(const short8*)(Bs[cur] + boff[i]);
    }
    #pragma unroll
    for (int i = 0; i < 4; ++i)
      #pragma unroll
      for (int j = 0; j < 4; ++j)
        acc[i][j] = __builtin_amdgcn_mfma_f32_16x16x32_bf16(af[i], bfr[j], acc[i][j], 0, 0, 0);

    __syncthreads();
  }

  float* Cp32 = (float*)Cout;
  if constexpr (EPI == 4) Cp32 += (size_t)blockIdx.z * ((size_t)M * N);

  #pragma unroll
  for (int i = 0; i < 4; ++i) {
    #pragma unroll
    for (int j = 0; j < 4; ++j) {
      const int rbase = m0 + wm + i * 16 + (lane >> 4) * 4;
      const int c = n0 + wn + j * 16 + (lane & 15);
      float bia = 0.0f;
      if constexpr (EPI != 4) bia = bias[c];
      #pragma unroll
      for (int r = 0; r < 4; ++r) {
        float v = acc[i][j][r] + bia;
        const size_t idx = (size_t)(rbase + r) * N + c;
        if constexpr (EPI == 0) {
          ((unsigned short*)Cout)[idx] = f2bits(v);
        } else if constexpr (EPI == 1) {
          ((float*)Cout)[idx] = v + resid[idx];
        } else if constexpr (EPI == 2) {
          v = 0.5f * v * (1.0f + erff(v * 0.70710678118654752f));
          ((unsigned short*)Cout)[idx] = f2bits(v);
        } else if constexpr (EPI == 3) {
          ((float*)Cout)[idx] = v + resid[idx];
        } else {
          Cp32[idx] = v;
        }
      }
    }
  }
}

// ---------------- 256x256 MFMA GEMM (qkv / fc1): 4-ring + counted vmcnt ----------------
template<int EPI>
__global__ __launch_bounds__(512) void gemm256_r17(
    const unsigned short* __restrict__ A,
    const unsigned short* __restrict__ BT,
    const float* __restrict__ bias,
    void* __restrict__ Cout,
    int M, int N, int K)
{
  __shared__ __align__(16) unsigned short As[4][256 * 32];
  __shared__ __align__(16) unsigned short Bs[4][256 * 32];
  const int tid = threadIdx.x;
  const int lane = tid & 63, wv = tid >> 6;
  const int quad = lane >> 4, l15 = lane & 15;
  const int m0 = blockIdx.y * 256, n0 = blockIdx.x * 256;
  const int wm = (wv >> 2) * 128, wn = (wv & 3) * 64;

  const int s0 = tid, s1 = tid + 512;
  const int r0 = s0 >> 2, kq0 = (s0 & 3) ^ ((r0 >> 1) & 3);
  const int r1 = s1 >> 2, kq1 = (s1 & 3) ^ ((r1 >> 1) & 3);
  const unsigned short* Ab = A  + (size_t)m0 * K;
  const unsigned short* Bb = BT + (size_t)n0 * K;
  const size_t ga0 = (size_t)r0 * K + kq0 * 8;
  const size_t ga1 = (size_t)r1 * K + kq1 * 8;

  floatx4 acc[8][4];
  #pragma unroll
  for (int i = 0; i < 8; ++i)
    #pragma unroll
    for (int j = 0; j < 4; ++j)
      acc[i][j] = (floatx4){0.f, 0.f, 0.f, 0.f};

  int aoff[8], boff[4];
  #pragma unroll
  for (int i = 0; i < 8; ++i) {
    int ra = wm + i * 16 + l15;
    aoff[i] = (ra * 4 + (quad ^ ((ra >> 1) & 3))) * 8;
  }
  #pragma unroll
  for (int j = 0; j < 4; ++j) {
    int rb = wn + j * 16 + l15;
    boff[j] = (rb * 4 + (quad ^ ((rb >> 1) & 3))) * 8;
  }

  #define STG_R17(t) { const size_t ko = (size_t)(t) * 32; const int bb = (t) & 3; \
    gld_lds16(Ab + ga0 + ko, As[bb] + s0 * 8); \
    gld_lds16(Ab + ga1 + ko, As[bb] + s1 * 8); \
    gld_lds16(Bb + ga0 + ko, Bs[bb] + s0 * 8); \
    gld_lds16(Bb + ga1 + ko, Bs[bb] + s1 * 8); }

  STG_R17(0);
  STG_R17(1);

  const int nsteps = K >> 5;
  for (int t = 0; t < nsteps; ++t) {
    const int cur = t & 3;
    if (t + 2 < nsteps) {
      STG_R17(t + 2);
      asm volatile("s_waitcnt vmcnt(8)" ::: "memory");
    } else if (t + 1 < nsteps) {
      asm volatile("s_waitcnt vmcnt(4)" ::: "memory");
    } else {
      asm volatile("s_waitcnt vmcnt(0)" ::: "memory");
    }
    __builtin_amdgcn_s_barrier();
    asm volatile("" ::: "memory");

    short8 bfr[4];
    #pragma unroll
    for (int j = 0; j < 4; ++j)
      bfr[j] = *(const short8*)(Bs[cur] + boff[j]);
    #pragma unroll
    for (int ih = 0; ih < 2; ++ih) {
      short8 af[4];
      #pragma unroll
      for (int k = 0; k < 4; ++k)
        af[k] = *(const short8*)(As[cur] + aoff[ih * 4 + k]);
      #pragma unroll
      for (int k = 0; k < 4; ++k)
        #pragma unroll
        for (int j = 0; j < 4; ++j)
          acc[ih * 4 + k][j] = __builtin_amdgcn_mfma_f32_16x16x32_bf16(af[k], bfr[j], acc[ih * 4 + k][j], 0, 0, 0);
    }
  }
  #undef STG_R17

  #pragma unroll
  for (int i = 0; i < 8; ++i) {
    #pragma unroll
    for (int j = 0; j < 4; ++j) {
      const int rbase = m0 + wm + i * 16 + quad * 4;
      const int c = n0 + wn + j * 16 + l15;
      const float bia = bias[c];
      #pragma unroll
      for (int r = 0; r < 4; ++r) {
        float v = acc[i][j][r] + bia;
        const size_t idx = (size_t)(rbase + r) * N + c;
        if constexpr (EPI == 2) {
          v = 0.5f * v * (1.0f + erff(v * 0.70710678118654752f));
        }
        ((unsigned short*)Cout)[idx] = f2bits(v);
      }
    }
  }
}

// ---------------- split-K reduce: out = P0 + P1 + resid + bias ----------------
__global__ __launch_bounds__(256) void red2_r17(const float* __restrict__ P,
                                                const float* __restrict__ resid,
                                                const float* __restrict__ bias,
                                                float* __restrict__ out)
{
  const size_t i = ((size_t)blockIdx.x * 256 + threadIdx.x) * 4;
  const int col = (int)(i & 1023);
  float4 p0 = *(const float4*)(P + i);
  float4 p1 = *(const float4*)(P + ((size_t)4096 * 1024) + i);
  float4 xr = *(const float4*)(resid + i);
  float4 b  = *(const float4*)(bias + col);
  float4 o  = { p0.x + p1.x + xr.x + b.x, p0.y + p1.y + xr.y + b.y,
                p0.z + p1.z + xr.z + b.z, p0.w + p1.w + xr.w + b.w };
  *(float4*)(out + i) = o;
}

// ---------------- MFMA flash attention (r17: 2-iter counted-vmcnt pipeline) ----------------
// qkv: [B*T, 3072] bf16. o: [B*T,1024] bf16. Grid dim3(8,32), 512 threads.
// qt pair (15-qt0, qt0) per block. Ks[3] ring; V regs double-buffered (loop
// unrolled x2; nkt = 2qt+2 is always even). Steady-state ledger: outstanding
// pre-issue = {K(t+1),V(t+1)} (3 ops); post-issue +{K(t+2),V(t+2)} = 6;
// vmcnt(3) at late-write retires t+1's ops, leaves t+2 flying across the
// raw s_barrier. Tail (t=nkt-2): vmcnt(0).
__global__ __launch_bounds__(512) void attn_r17(const unsigned short* __restrict__ qkv,
                                                unsigned short* __restrict__ o)
{
  __shared__ __align__(16) unsigned short Qs[128 * 64];      // swizzled chunks
  __shared__ __align__(16) unsigned short Ks[3][64 * 64];    // 3-ring, swizzled
  __shared__ __align__(16) unsigned short VT[2][64 * 72];    // dbuf, [d][tok] pad 72
  __shared__ __align__(16) unsigned short Ps[128 * 72];      // [q][tok] pad 72 (wave-own)
  __shared__ __align__(16) float stat_s[128];                // alpha / l (wave-own)

  const int tid = threadIdx.x, lane = tid & 63, wv = tid >> 6;
  const int quad = lane >> 4, l15 = lane & 15;
  const int qt0 = blockIdx.x, bh = blockIdx.y;
  const int b = bh >> 4, h = bh & 15;
  const size_t base = (size_t)b * 2048 * 3072;
  const int qcol = h * 64, kcol = 1024 + h * 64, vcol = 2048 + h * 64;

  const int sr = tid >> 3, scp = tid & 7, sc = scp ^ (sr & 7);
  const unsigned short* kgp = qkv + base + (size_t)sr * 3072 + kcol + sc * 8;
  const int vp = tid & 31, vdc = tid >> 5;
  const unsigned short* vgp = qkv + base + (size_t)(2 * vp) * 3072 + vcol + vdc * 4;
  unsigned short* KsB = &Ks[0][0];
  const int t8 = tid * 8;

  for (int pass = 0; pass < 2; ++pass) {
    const int qt = pass ? qt0 : 15 - qt0;
    const int q0 = qt * 128;
    const int nkt = 2 * qt + 2;

    __syncthreads();  // prior pass fully done (drains everything once per pass)

    // ---- prologue: stage Q, K0, K1, V0, V1 (8 vm-ops) ----
    #pragma unroll
    for (int p = 0; p < 2; ++p) {
      int s = tid + 512 * p;
      int r = s >> 3, cp = s & 7, c = cp ^ (r & 7);
      gld_lds16(qkv + base + (size_t)(q0 + r) * 3072 + qcol + c * 8, Qs + s * 8);
    }
    gld_lds16(kgp, KsB + t8);
    uint2 vA0, vA1, vB0, vB1;
    if (nkt > 1) gld_lds16(kgp + (size_t)64 * 3072, KsB + 4096 + t8);
    vA0 = *(const uint2*)vgp;
    vA1 = *(const uint2*)(vgp + 3072);
    if (nkt > 1) {
      vB0 = *(const uint2*)(vgp + (size_t)64 * 3072);
      vB1 = *(const uint2*)(vgp + (size_t)64 * 3072 + 3072);
    }
    asm volatile("s_waitcnt vmcnt(2)" ::: "memory");   // Q,K0,K1,V0 landed; V1 flying
    {
      unsigned short* dst = VT[0] + (size_t)(vdc * 4) * 72 + 2 * vp;
      *(unsigned int*)(dst + 0 * 72) = (vA0.x & 0xffffu) | (vA1.x << 16);
      *(unsigned int*)(dst + 1 * 72) = (vA0.x >> 16)     | (vA1.x & 0xffff0000u);
      *(unsigned int*)(dst + 2 * 72) = (vA0.y & 0xffffu) | (vA1.y << 16);
      *(unsigned int*)(dst + 3 * 72) = (vA0.y >> 16)     | (vA1.y & 0xffff0000u);
    }
    asm volatile("s_waitcnt lgkmcnt(0)" ::: "memory");
    __builtin_amdgcn_s_barrier();

    // ---- preload Q A-frags ----
    short8 qa[2];
    #pragma unroll
    for (int ks = 0; ks < 2; ++ks) {
      int ra = wv * 16 + l15;
      int cp = (ks * 4 + quad) ^ (ra & 7);
      qa[ks] = *(const short8*)(Qs + (ra * 8 + cp) * 8);
    }

    floatx4 oacc[4];
    #pragma unroll
    for (int dt = 0; dt < 4; ++dt) oacc[dt] = (floatx4){0.f, 0.f, 0.f, 0.f};
    float m_i[4], l_i[4];
    #pragma unroll
    for (int r = 0; r < 4; ++r) { m_i[r] = -3.0e38f; l_i[r] = 0.0f; }

    // ---- main loop, unrolled x2 (nkt even). even iter: load->vA, write vB;
    //      odd iter: load->vB, write vA. ----
#define AITER_R17(KT, LV0, LV1, WV0, WV1)                                        \
    {                                                                            \
      const int kt_ = (KT);                                                      \
      const bool pf2_ = (kt_ + 2 < nkt);                                         \
      const bool pf1_ = (kt_ + 1 < nkt);                                         \
      if (pf2_) {                                                                \
        const size_t koff_ = (size_t)(kt_ + 2) * 64 * 3072;                      \
        gld_lds16(kgp + koff_, KsB + ((kt_ + 2) % 3) * 4096 + t8);               \
        LV0 = *(const uint2*)(vgp + koff_);                                      \
        LV1 = *(const uint2*)(vgp + koff_ + 3072);                               \
      }                                                                          \
      const unsigned short* Kcur_ = KsB + (kt_ % 3) * 4096;                      \
      const unsigned short* Vcur_ = VT[kt_ & 1];                                 \
      short8 kb[4][2];                                                           \
      _Pragma("unroll")                                                          \
      for (int j = 0; j < 4; ++j)                                                \
        _Pragma("unroll")                                                        \
        for (int ks = 0; ks < 2; ++ks) {                                         \
          int rb = j * 16 + l15;                                                 \
          int cp = (ks * 4 + quad) ^ (rb & 7);                                   \
          kb[j][ks] = *(const short8*)(Kcur_ + (rb * 8 + cp) * 8);               \
        }                                                                        \
      floatx4 s_[4];                                                             \
      _Pragma("unroll")                                                          \
      for (int j = 0; j < 4; ++j) s_[j] = (floatx4){0.f, 0.f, 0.f, 0.f};         \
      _Pragma("unroll")                                                          \
      for (int j = 0; j < 4; ++j)                                                \
        _Pragma("unroll")                                                        \
        for (int ks = 0; ks < 2; ++ks)                                           \
          s_[j] = __builtin_amdgcn_mfma_f32_16x16x32_bf16(qa[ks], kb[j][ks], s_[j], 0, 0, 0); \
      const int k0_ = kt_ * 64;                                                  \
      const int rowmin_ = q0 + wv * 16;                                          \
      const int rowb_ = rowmin_ + quad * 4;                                      \
      if (k0_ + 63 > rowmin_) {                                                  \
        _Pragma("unroll")                                                        \
        for (int j = 0; j < 4; ++j) {                                            \
          const int col_ = k0_ + j * 16 + l15;                                   \
          _Pragma("unroll")                                                      \
          for (int r = 0; r < 4; ++r)                                            \
            if (col_ > rowb_ + r) s_[j][r] = -3.0e38f;                           \
        }                                                                        \
      }                                                                          \
      float fm[4], al[4], rs[4];                                                 \
      _Pragma("unroll")                                                          \
      for (int r = 0; r < 4; ++r)                                                \
        fm[r] = fmaxf(fmaxf(s_[0][r], s_[1][r]), fmaxf(s_[2][r], s_[3][r]));     \
      _Pragma("unroll")                                                          \
      for (int msk = 1; msk < 16; msk <<= 1)                                     \
        _Pragma("unroll")                                                        \
        for (int r = 0; r < 4; ++r)                                              \
          fm[r] = fmaxf(fm[r], __shfl_xor(fm[r], msk, 64));                      \
      _Pragma("unroll")                                                          \
      for (int r = 0; r < 4; ++r) {                                              \
        const float mn = fmaxf(m_i[r], fm[r]);                                   \
        al[r] = __expf(m_i[r] - mn);                                             \
        m_i[r] = mn;                                                             \
      }                                                                          \
      _Pragma("unroll")                                                          \
      for (int j = 0; j < 4; ++j)                                                \
        _Pragma("unroll")                                                        \
        for (int r = 0; r < 4; ++r)                                              \
          s_[j][r] = __expf(s_[j][r] - m_i[r]);                                  \
      _Pragma("unroll")                                                          \
      for (int r = 0; r < 4; ++r)                                                \
        rs[r] = (s_[0][r] + s_[1][r]) + (s_[2][r] + s_[3][r]);                   \
      _Pragma("unroll")                                                          \
      for (int msk = 1; msk < 16; msk <<= 1)                                     \
        _Pragma("unroll")                                                        \
        for (int r = 0; r < 4; ++r)                                              \
          rs[r] += __shfl_xor(rs[r], msk, 64);                                   \
      _Pragma("unroll")                                                          \
      for (int r = 0; r < 4; ++r)                                                \
        l_i[r] = l_i[r] * al[r] + rs[r];                                         \
      if (l15 == 0) {                                                            \
        float4 a4 = { al[0], al[1], al[2], al[3] };                              \
        *(float4*)(stat_s + wv * 16 + quad * 4) = a4;                            \
      }                                                                          \
      _Pragma("unroll")                                                          \
      for (int j = 0; j < 4; ++j)                                                \
        _Pragma("unroll")                                                        \
        for (int r = 0; r < 4; ++r)                                              \
          Ps[(size_t)(wv * 16 + quad * 4 + r) * 72 + j * 16 + l15] = f2bits(s_[j][r]); \
      const float alq_ = stat_s[wv * 16 + l15];                                  \
      _Pragma("unroll")                                                          \
      for (int dt = 0; dt < 4; ++dt)                                             \
        _Pragma("unroll")                                                        \
        for (int r = 0; r < 4; ++r)                                              \
          oacc[dt][r] *= alq_;                                                   \
      short8 va[4][2], pb[2];                                                    \
      _Pragma("unroll")                                                          \
      for (int dt = 0; dt < 4; ++dt)                                             \
        _Pragma("unroll")                                                        \
        for (int ks = 0; ks < 2; ++ks)                                           \
          va[dt][ks] = *(const short8*)(Vcur_ + (size_t)(dt * 16 + l15) * 72 + ks * 32 + quad * 8); \
      _Pragma("unroll")                                                          \
      for (int ks = 0; ks < 2; ++ks)                                             \
        pb[ks] = *(const short8*)(Ps + (size_t)(wv * 16 + l15) * 72 + ks * 32 + quad * 8); \
      _Pragma("unroll")                                                          \
      for (int dt = 0; dt < 4; ++dt)                                             \
        _Pragma("unroll")                                                        \
        for (int ks = 0; ks < 2; ++ks)                                           \
          oacc[dt] = __builtin_amdgcn_mfma_f32_16x16x32_bf16(va[dt][ks], pb[ks], oacc[dt], 0, 0, 0); \
      if (pf1_) {                                                                \
        if (pf2_) { asm volatile("s_waitcnt vmcnt(3)" ::: "memory"); }           \
        else      { asm volatile("s_waitcnt vmcnt(0)" ::: "memory"); }           \
        unsigned short* dst = VT[(kt_ + 1) & 1] + (size_t)(vdc * 4) * 72 + 2 * vp; \
        *(unsigned int*)(dst + 0 * 72) = (WV0.x & 0xffffu) | (WV1.x << 16);      \
        *(unsigned int*)(dst + 1 * 72) = (WV0.x >> 16)     | (WV1.x & 0xffff0000u); \
        *(unsigned int*)(dst + 2 * 72) = (WV0.y & 0xffffu) | (WV1.y << 16);      \
        *(unsigned int*)(dst + 3 * 72) = (WV0.y >> 16)     | (WV1.y & 0xffff0000u); \
      }                                                                          \
      asm volatile("s_waitcnt lgkmcnt(0)" ::: "memory");                         \
      __builtin_amdgcn_s_barrier();                                              \
    }

    for (int t = 0; t < nkt; t += 2) {
      AITER_R17(t,     vA0, vA1, vB0, vB1);   // even: load V(t+2)->vA, write V(t+1)=vB
      AITER_R17(t + 1, vB0, vB1, vA0, vA1);   // odd:  load V(t+3)->vB, write V(t+2)=vA
    }
#undef AITER_R17

    // ---- epilogue: O = O^T / l * 32^-1 ----
    if (l15 == 0) {
      float4 l4 = { l_i[0], l_i[1], l_i[2], l_i[3] };
      *(float4*)(stat_s + wv * 16 + quad * 4) = l4;
    }
    const float linv = 0.03125f / stat_s[wv * 16 + l15];
    const size_t row = (size_t)b * 2048 + q0 + wv * 16 + l15;
    #pragma unroll
    for (int dt = 0; dt < 4; ++dt) {
      const int col = h * 64 + dt * 16 + quad * 4;
      ushort4 o4 = { f2bits(oacc[dt][0] * linv), f2bits(oacc[dt][1] * linv),
                     f2bits(oacc[dt][2] * linv), f2bits(oacc[dt][3] * linv) };
      *(ushort4*)(o + row * 1024 + col) = o4;
    }
  }
}

extern "C" void kernel_launch(void* const* d_in, const int* in_sizes, int n_in,
                              void* d_out, int out_size, void* d_ws, size_t ws_size,
                              hipStream_t stream)
{
  (void)in_sizes; (void)n_in; (void)out_size; (void)ws_size;
  const float* x      = (const float*)d_in[0];
  const float* w_attn = (const float*)d_in[1];
  const float* b_attn = (const float*)d_in[2];
  const float* w_proj = (const float*)d_in[3];
  const float* b_proj = (const float*)d_in[4];
  const float* w_fc1  = (const float*)d_in[5];
  const float* b_fc1  = (const float*)d_in[6];
  const float* w_fc2  = (const float*)d_in[7];
  const float* b_fc2  = (const float*)d_in[8];
  const float* g1     = (const float*)d_in[9];
  const float* g2     = (const float*)d_in[10];
  float* out = (float*)d_out;

  // ws layout (88 MB): h/ov bf16 @0 (8MB), qkv bf16 @8MB (24MB, h2 reuses 8..16MB),
  //                    x1 f32 @32MB (16MB), h3 bf16 @48MB (32MB), WT scratch @80MB (8MB)
  // fc2 split-K partials (2 x 16MB f32) reuse 0..32MB (h/h2/qkv/ov all dead there).
  char* ws = (char*)d_ws;
  unsigned short* h   = (unsigned short*)(ws);
  unsigned short* qkv = (unsigned short*)(ws + ((size_t)8  << 20));
  unsigned short* ov  = (unsigned short*)(ws);                       // reuse h
  float*          x1  = (float*)         (ws + ((size_t)32 << 20));
  unsigned short* h2  = (unsigned short*)(ws + ((size_t)8  << 20));  // reuse qkv
  unsigned short* h3  = (unsigned short*)(ws + ((size_t)48 << 20));
  unsigned short* WT  = (unsigned short*)(ws + ((size_t)80 << 20));
  float*          P   = (float*)(ws);                                // fc2 split-K partials

  const int M = 4096;

  rmsnorm_r17<<<M, 256, 0, stream>>>(x, g1, h);
  wprep_r17<<<dim3(3072 / 32, 1024 / 32), 256, 0, stream>>>(w_attn, WT, 1024, 3072);
  gemm256_r17<0><<<dim3(3072 / 256, M / 256), 512, 0, stream>>>(h, WT, b_attn, qkv, M, 3072, 1024);
  attn_r17<<<dim3(8, 32), 512, 0, stream>>>(qkv, ov);
  wprep_r17<<<dim3(1024 / 32, 1024 / 32), 256, 0, stream>>>(w_proj, WT, 1024, 1024);
  gemm128_r17<1><<<dim3(1024 / 128, M / 128), 256, 0, stream>>>(ov, WT, b_proj, x, x1, M, 1024, 1024, 1024);
  rmsnorm_r17<<<M, 256, 0, stream>>>(x1, g2, h2);
  wprep_r17<<<dim3(4096 / 32, 1024 / 32), 256, 0, stream>>>(w_fc1, WT, 1024, 4096);
  gemm256_r17<2><<<dim3(4096 / 256, M / 256), 512, 0, stream>>>(h2, WT, b_fc1, h3, M, 4096, 1024);
  wprep_r17<<<dim3(1024 / 32, 4096 / 32), 256, 0, stream>>>(w_fc2, WT, 4096, 1024);
  gemm128_r17<4><<<dim3(1024 / 128, M / 128, 2), 256, 0, stream>>>(h3, WT, nullptr, nullptr, P, M, 1024, 4096, 2048);
  red2_r17<<<4096, 256, 0, stream>>>(P, x1, b_fc2, out);
}

// Round 10
// 369.974 us; speedup vs baseline: 1.2257x; 1.0532x over previous
//
#include <hip/hip_runtime.h>
#include <hip/hip_bf16.h>

// Transformer block for MI355X. Round 18: attention KVBLK 64->128.
//  - r17 falsified the staging-drain theory (deeper pipeline hurt). r16
//    showed weak TLP scaling. => per-iter FIXED serial work dominates
//    (2x 4-step shuffle chains, stat_s round-trip, P-write landing, barrier).
//  - r18: halve the iteration count (34->17 per block) by processing 128
//    K-tokens per iter. Same total MFMA/expf/LDS bytes; fixed costs halved.
//    r15 pipeline shape kept (1-deep prefetch, one barrier/iter). LDS 118KB
//    (1 block/CU is established reality). Pads keep 2-way-max bank aliasing.
//  - gemm256 (qkv/fc1), gemm128 (proj/fc2-splitK), rmsnorm, wprep, red2
//    unchanged from r15 (379.4us baseline).
// All symbols _r18 (fresh build).

typedef __hip_bfloat16 bf16;
typedef __attribute__((ext_vector_type(8))) short short8;   // 8 bf16 = 4 VGPRs
typedef __attribute__((ext_vector_type(4))) float floatx4;  // MFMA C/D frag

__device__ __forceinline__ float bits2f(unsigned short u) {
  union { unsigned int i; float f; } c; c.i = ((unsigned int)u) << 16; return c.f;
}
__device__ __forceinline__ unsigned short f2bits(float f) {
  bf16 b = __float2bfloat16(f);
  union { bf16 b; unsigned short u; } c; c.b = b; return c.u;
}

__device__ __forceinline__ void gld_lds16(const unsigned short* g, unsigned short* l) {
  __builtin_amdgcn_global_load_lds(
      (const __attribute__((address_space(1))) void*)g,
      (__attribute__((address_space(3))) void*)l, 16, 0, 0);
}

// ---------------- RMSNorm: f32 in, f32 gamma, bf16 out ----------------
__global__ __launch_bounds__(256) void rmsnorm_r18(const float* __restrict__ x,
                                                   const float* __restrict__ g,
                                                   unsigned short* __restrict__ out)
{
  const int row = blockIdx.x, tid = threadIdx.x;
  const size_t rb = (size_t)row * 1024;
  float4 xv = *(const float4*)(x + rb + tid * 4);
  float v[4] = {xv.x, xv.y, xv.z, xv.w};
  float s = v[0]*v[0] + v[1]*v[1] + v[2]*v[2] + v[3]*v[3];
  #pragma unroll
  for (int off = 32; off > 0; off >>= 1) s += __shfl_down(s, off, 64);
  __shared__ float part[4];
  if ((tid & 63) == 0) part[tid >> 6] = s;
  __syncthreads();
  const float tot = part[0] + part[1] + part[2] + part[3];
  const float sc = rsqrtf(tot * (1.0f / 1024.0f) + 1.1920929e-07f);
  float4 gv = *(const float4*)(g + tid * 4);
  ushort4 o4 = { f2bits(v[0] * sc * gv.x), f2bits(v[1] * sc * gv.y),
                 f2bits(v[2] * sc * gv.z), f2bits(v[3] * sc * gv.w) };
  *(ushort4*)(out + rb + tid * 4) = o4;
}

// ---------------- Weight prep: W f32 [K,N] -> WT bf16 [N,K] ----------------
__global__ __launch_bounds__(256) void wprep_r18(const float* __restrict__ in,
                                                 unsigned short* __restrict__ out,
                                                 int K, int N)
{
  __shared__ unsigned short tile[32][33];
  const int tid = threadIdx.x;
  const int k0 = blockIdx.y * 32, n0 = blockIdx.x * 32;
  const int tr = tid >> 3, tc4 = (tid & 7) * 4;
  float4 v = *(const float4*)(in + (size_t)(k0 + tr) * N + n0 + tc4);
  tile[tr][tc4 + 0] = f2bits(v.x);
  tile[tr][tc4 + 1] = f2bits(v.y);
  tile[tr][tc4 + 2] = f2bits(v.z);
  tile[tr][tc4 + 3] = f2bits(v.w);
  __syncthreads();
  ushort4 o = { tile[tc4 + 0][tr], tile[tc4 + 1][tr],
                tile[tc4 + 2][tr], tile[tc4 + 3][tr] };
  *(ushort4*)(out + (size_t)(n0 + tr) * K + k0 + tc4) = o;
}

// ---------------- 128x128 MFMA GEMM (proj / fc2-splitK) ----------------
// EPI: 0=bf16  1=f32+resid  2=gelu->bf16  3=f32+resid  4=f32 partial (split-K)
template<int EPI>
__global__ __launch_bounds__(256) void gemm128_r18(
    const unsigned short* __restrict__ A,
    const unsigned short* __restrict__ BT,
    const float* __restrict__ bias,
    const float* __restrict__ resid,
    void* __restrict__ Cout,
    int M, int N, int K, int Klen)
{
  __shared__ __align__(16) unsigned short As[2][128 * 32];
  __shared__ __align__(16) unsigned short Bs[2][128 * 32];
  const int tid = threadIdx.x;
  const int lane = tid & 63;
  const int wv = tid >> 6;
  const int m0 = blockIdx.y * 128, n0 = blockIdx.x * 128;
  const int wm = (wv >> 1) * 64, wn = (wv & 1) * 64;
  const int kbase = blockIdx.z * Klen;

  const int s0 = tid, s1 = tid + 256;
  const int r0 = s0 >> 2, kq0 = (s0 & 3) ^ ((r0 >> 1) & 3);
  const int r1 = s1 >> 2, kq1 = (s1 & 3) ^ ((r1 >> 1) & 3);
  const unsigned short* Ab = A  + (size_t)m0 * K;
  const unsigned short* Bb = BT + (size_t)n0 * K;
  const size_t ga0 = (size_t)r0 * K + kq0 * 8 + kbase;
  const size_t ga1 = (size_t)r1 * K + kq1 * 8 + kbase;

  floatx4 acc[4][4];
  #pragma unroll
  for (int i = 0; i < 4; ++i)
    #pragma unroll
    for (int j = 0; j < 4; ++j)
      acc[i][j] = (floatx4){0.f, 0.f, 0.f, 0.f};

  int aoff[4], boff[4];
  #pragma unroll
  for (int i = 0; i < 4; ++i) {
    int ra = wm + i * 16 + (lane & 15);
    aoff[i] = (ra * 4 + ((lane >> 4) ^ ((ra >> 1) & 3))) * 8;
    int rb = wn + i * 16 + (lane & 15);
    boff[i] = (rb * 4 + ((lane >> 4) ^ ((rb >> 1) & 3))) * 8;
  }

  gld_lds16(Ab + ga0, As[0] + s0 * 8);
  gld_lds16(Ab + ga1, As[0] + s1 * 8);
  gld_lds16(Bb + ga0, Bs[0] + s0 * 8);
  gld_lds16(Bb + ga1, Bs[0] + s1 * 8);
  __syncthreads();

  const int nsteps = Klen >> 5;
  for (int t = 0; t < nsteps; ++t) {
    const int cur = t & 1;
    if (t + 1 < nsteps) {
      const size_t ko = (size_t)(t + 1) * 32;
      gld_lds16(Ab + ga0 + ko, As[cur ^ 1] + s0 * 8);
      gld_lds16(Ab + ga1 + ko, As[cur ^ 1] + s1 * 8);
      gld_lds16(Bb + ga0 + ko, Bs[cur ^ 1] + s0 * 8);
      gld_lds16(Bb + ga1 + ko, Bs[cur ^ 1] + s1 * 8);
    }

    short8 af[4], bfr[4];
    #pragma unroll
    for (int i = 0; i < 4; ++i) {
      af[i]  = *(const short8*)(As[cur] + aoff[i]);
      bfr[i] = *(const short8*)(Bs[cur] + boff[i]);
    }
    #pragma unroll
    for (int i = 0; i < 4; ++i)
      #pragma unroll
      for (int j = 0; j < 4; ++j)
        acc[i][j] = __builtin_amdgcn_mfma_f32_16x16x32_bf16(af[i], bfr[j], acc[i][j], 0, 0, 0);

    __syncthreads();
  }

  float* Cp32 = (float*)Cout;
  if constexpr (EPI == 4) Cp32 += (size_t)blockIdx.z * ((size_t)M * N);

  #pragma unroll
  for (int i = 0; i < 4; ++i) {
    #pragma unroll
    for (int j = 0; j < 4; ++j) {
      const int rbase = m0 + wm + i * 16 + (lane >> 4) * 4;
      const int c = n0 + wn + j * 16 + (lane & 15);
      float bia = 0.0f;
      if constexpr (EPI != 4) bia = bias[c];
      #pragma unroll
      for (int r = 0; r < 4; ++r) {
        float v = acc[i][j][r] + bia;
        const size_t idx = (size_t)(rbase + r) * N + c;
        if constexpr (EPI == 0) {
          ((unsigned short*)Cout)[idx] = f2bits(v);
        } else if constexpr (EPI == 1) {
          ((float*)Cout)[idx] = v + resid[idx];
        } else if constexpr (EPI == 2) {
          v = 0.5f * v * (1.0f + erff(v * 0.70710678118654752f));
          ((unsigned short*)Cout)[idx] = f2bits(v);
        } else if constexpr (EPI == 3) {
          ((float*)Cout)[idx] = v + resid[idx];
        } else {
          Cp32[idx] = v;
        }
      }
    }
  }
}

// ---------------- 256x256 MFMA GEMM (qkv / fc1): 4-ring + counted vmcnt ----------------
template<int EPI>
__global__ __launch_bounds__(512) void gemm256_r18(
    const unsigned short* __restrict__ A,
    const unsigned short* __restrict__ BT,
    const float* __restrict__ bias,
    void* __restrict__ Cout,
    int M, int N, int K)
{
  __shared__ __align__(16) unsigned short As[4][256 * 32];
  __shared__ __align__(16) unsigned short Bs[4][256 * 32];
  const int tid = threadIdx.x;
  const int lane = tid & 63, wv = tid >> 6;
  const int quad = lane >> 4, l15 = lane & 15;
  const int m0 = blockIdx.y * 256, n0 = blockIdx.x * 256;
  const int wm = (wv >> 2) * 128, wn = (wv & 3) * 64;

  const int s0 = tid, s1 = tid + 512;
  const int r0 = s0 >> 2, kq0 = (s0 & 3) ^ ((r0 >> 1) & 3);
  const int r1 = s1 >> 2, kq1 = (s1 & 3) ^ ((r1 >> 1) & 3);
  const unsigned short* Ab = A  + (size_t)m0 * K;
  const unsigned short* Bb = BT + (size_t)n0 * K;
  const size_t ga0 = (size_t)r0 * K + kq0 * 8;
  const size_t ga1 = (size_t)r1 * K + kq1 * 8;

  floatx4 acc[8][4];
  #pragma unroll
  for (int i = 0; i < 8; ++i)
    #pragma unroll
    for (int j = 0; j < 4; ++j)
      acc[i][j] = (floatx4){0.f, 0.f, 0.f, 0.f};

  int aoff[8], boff[4];
  #pragma unroll
  for (int i = 0; i < 8; ++i) {
    int ra = wm + i * 16 + l15;
    aoff[i] = (ra * 4 + (quad ^ ((ra >> 1) & 3))) * 8;
  }
  #pragma unroll
  for (int j = 0; j < 4; ++j) {
    int rb = wn + j * 16 + l15;
    boff[j] = (rb * 4 + (quad ^ ((rb >> 1) & 3))) * 8;
  }

  #define STG_R18(t) { const size_t ko = (size_t)(t) * 32; const int bb = (t) & 3; \
    gld_lds16(Ab + ga0 + ko, As[bb] + s0 * 8); \
    gld_lds16(Ab + ga1 + ko, As[bb] + s1 * 8); \
    gld_lds16(Bb + ga0 + ko, Bs[bb] + s0 * 8); \
    gld_lds16(Bb + ga1 + ko, Bs[bb] + s1 * 8); }

  STG_R18(0);
  STG_R18(1);

  const int nsteps = K >> 5;
  for (int t = 0; t < nsteps; ++t) {
    const int cur = t & 3;
    if (t + 2 < nsteps) {
      STG_R18(t + 2);
      asm volatile("s_waitcnt vmcnt(8)" ::: "memory");
    } else if (t + 1 < nsteps) {
      asm volatile("s_waitcnt vmcnt(4)" ::: "memory");
    } else {
      asm volatile("s_waitcnt vmcnt(0)" ::: "memory");
    }
    __builtin_amdgcn_s_barrier();
    asm volatile("" ::: "memory");

    short8 bfr[4];
    #pragma unroll
    for (int j = 0; j < 4; ++j)
      bfr[j] = *(const short8*)(Bs[cur] + boff[j]);
    #pragma unroll
    for (int ih = 0; ih < 2; ++ih) {
      short8 af[4];
      #pragma unroll
      for (int k = 0; k < 4; ++k)
        af[k] = *(const short8*)(As[cur] + aoff[ih * 4 + k]);
      #pragma unroll
      for (int k = 0; k < 4; ++k)
        #pragma unroll
        for (int j = 0; j < 4; ++j)
          acc[ih * 4 + k][j] = __builtin_amdgcn_mfma_f32_16x16x32_bf16(af[k], bfr[j], acc[ih * 4 + k][j], 0, 0, 0);
    }
  }
  #undef STG_R18

  #pragma unroll
  for (int i = 0; i < 8; ++i) {
    #pragma unroll
    for (int j = 0; j < 4; ++j) {
      const int rbase = m0 + wm + i * 16 + quad * 4;
      const int c = n0 + wn + j * 16 + l15;
      const float bia = bias[c];
      #pragma unroll
      for (int r = 0; r < 4; ++r) {
        float v = acc[i][j][r] + bia;
        const size_t idx = (size_t)(rbase + r) * N + c;
        if constexpr (EPI == 2) {
          v = 0.5f * v * (1.0f + erff(v * 0.70710678118654752f));
        }
        ((unsigned short*)Cout)[idx] = f2bits(v);
      }
    }
  }
}

// ---------------- split-K reduce: out = P0 + P1 + resid + bias ----------------
__global__ __launch_bounds__(256) void red2_r18(const float* __restrict__ P,
                                                const float* __restrict__ resid,
                                                const float* __restrict__ bias,
                                                float* __restrict__ out)
{
  const size_t i = ((size_t)blockIdx.x * 256 + threadIdx.x) * 4;
  const int col = (int)(i & 1023);
  float4 p0 = *(const float4*)(P + i);
  float4 p1 = *(const float4*)(P + ((size_t)4096 * 1024) + i);
  float4 xr = *(const float4*)(resid + i);
  float4 b  = *(const float4*)(bias + col);
  float4 o  = { p0.x + p1.x + xr.x + b.x, p0.y + p1.y + xr.y + b.y,
                p0.z + p1.z + xr.z + b.z, p0.w + p1.w + xr.w + b.w };
  *(float4*)(out + i) = o;
}

// ---------------- MFMA flash attention (r18: KVBLK=128, 17 iters/block) ----------------
// qkv: [B*T, 3072] bf16 (q|k|v, each 16 heads x 64). o: [B*T,1024] bf16.
// Grid dim3(8,32), 512 threads. qt pair (15-qt0, qt0) per block; nkt = qt+1
// per pass -> (16-qt0)+(qt0+1) = 17 iters/block uniform. r15 pipeline shape:
// issue next K DMA (2x16B/thread) + next V uint4 regs at top, one barrier.
// LDS ~118KB (1 block/CU established). Pads 136 shorts = 68 dwords (== 4
// mod 32) keep reads at free 2-way aliasing.
__global__ __launch_bounds__(512) void attn_r18(const unsigned short* __restrict__ qkv,
                                                unsigned short* __restrict__ o)
{
  __shared__ __align__(16) unsigned short Qs[128 * 64];       // 16KB swizzled
  __shared__ __align__(16) unsigned short Ks[2][128 * 64];    // 2x16KB dbuf, swizzled
  __shared__ __align__(16) unsigned short VT[2][64 * 136];    // dbuf, [d][tok] pad 136
  __shared__ __align__(16) unsigned short Ps[128 * 136];      // [q][tok] pad 136
  __shared__ __align__(16) float stat_s[128];                 // alpha / l (wave-own)

  const int tid = threadIdx.x, lane = tid & 63, wv = tid >> 6;
  const int quad = lane >> 4, l15 = lane & 15;
  const int qt0 = blockIdx.x, bh = blockIdx.y;
  const int b = bh >> 4, h = bh & 15;
  const size_t base = (size_t)b * 2048 * 3072;
  const int qcol = h * 64, kcol = 1024 + h * 64, vcol = 2048 + h * 64;

  // K staging: 1024 slots of 16B; slot s=tid and s+512 (row +64, same chunk col)
  const int sr = tid >> 3, scp = tid & 7, sc = scp ^ (sr & 7);
  const unsigned short* kgp = qkv + base + (size_t)sr * 3072 + kcol + sc * 8;
  // V staging: vp = tok pair (0..63), vdc = 8-dim group (0..7)
  const int vp = tid & 63, vdc = tid >> 6;
  const unsigned short* vgp = qkv + base + (size_t)(2 * vp) * 3072 + vcol + vdc * 8;

  for (int pass = 0; pass < 2; ++pass) {
    const int qt = pass ? qt0 : 15 - qt0;
    const int q0 = qt * 128;
    const int nkt = qt + 1;

    __syncthreads();  // prior pass fully done before restage

    // ---- stage Q (1024 slots, chunk-XOR swizzle cp = c ^ (row&7)) ----
    #pragma unroll
    for (int p = 0; p < 2; ++p) {
      int s = tid + 512 * p;
      int r = s >> 3, cp = s & 7, c = cp ^ (r & 7);
      gld_lds16(qkv + base + (size_t)(q0 + r) * 3072 + qcol + c * 8, Qs + s * 8);
    }
    // ---- stage K tile 0 (both 64-row halves) ----
    gld_lds16(kgp, Ks[0] + tid * 8);
    gld_lds16(kgp + (size_t)64 * 3072, Ks[0] + (size_t)(tid + 512) * 8);
    // ---- stage V tile 0 (uint4 reg load + transpose pack) ----
    {
      uint4 u0 = *(const uint4*)vgp;
      uint4 u1 = *(const uint4*)(vgp + 3072);
      unsigned short* dst = VT[0] + (size_t)(vdc * 8) * 136 + 2 * vp;
      *(unsigned int*)(dst + 0 * 136) = (u0.x & 0xffffu) | (u1.x << 16);
      *(unsigned int*)(dst + 1 * 136) = (u0.x >> 16)     | (u1.x & 0xffff0000u);
      *(unsigned int*)(dst + 2 * 136) = (u0.y & 0xffffu) | (u1.y << 16);
      *(unsigned int*)(dst + 3 * 136) = (u0.y >> 16)     | (u1.y & 0xffff0000u);
      *(unsigned int*)(dst + 4 * 136) = (u0.z & 0xffffu) | (u1.z << 16);
      *(unsigned int*)(dst + 5 * 136) = (u0.z >> 16)     | (u1.z & 0xffff0000u);
      *(unsigned int*)(dst + 6 * 136) = (u0.w & 0xffffu) | (u1.w << 16);
      *(unsigned int*)(dst + 7 * 136) = (u0.w >> 16)     | (u1.w & 0xffff0000u);
    }
    __syncthreads();

    // ---- preload Q A-frags (row = wave q-row, k = dim) ----
    short8 qa[2];
    #pragma unroll
    for (int ks = 0; ks < 2; ++ks) {
      int ra = wv * 16 + l15;
      int cp = (ks * 4 + quad) ^ (ra & 7);
      qa[ks] = *(const short8*)(Qs + (ra * 8 + cp) * 8);
    }

    floatx4 oacc[4];
    #pragma unroll
    for (int dt = 0; dt < 4; ++dt) oacc[dt] = (floatx4){0.f, 0.f, 0.f, 0.f};
    float m_i[4], l_i[4];
    #pragma unroll
    for (int r = 0; r < 4; ++r) { m_i[r] = -3.0e38f; l_i[r] = 0.0f; }

    for (int kt = 0; kt < nkt; ++kt) {
      const int cur = kt & 1;
      const bool pf = (kt + 1 < nkt);
      uint4 u0, u1;
      if (pf) {  // issue next-tile loads NOW; latency hides under compute below
        const size_t koff = (size_t)(kt + 1) * 128 * 3072;
        gld_lds16(kgp + koff, Ks[cur ^ 1] + tid * 8);
        gld_lds16(kgp + koff + (size_t)64 * 3072, Ks[cur ^ 1] + (size_t)(tid + 512) * 8);
        u0 = *(const uint4*)(vgp + koff);
        u1 = *(const uint4*)(vgp + koff + 3072);
      }

      // ---- S = Q K^T over 8 col-tiles (from Ks[cur]) ----
      floatx4 s_[8];
      #pragma unroll
      for (int j = 0; j < 8; ++j) s_[j] = (floatx4){0.f, 0.f, 0.f, 0.f};
      #pragma unroll
      for (int j = 0; j < 8; ++j) {
        const int rb = j * 16 + l15;
        short8 kb0 = *(const short8*)(Ks[cur] + (rb * 8 + ((quad    ) ^ (rb & 7))) * 8);
        short8 kb1 = *(const short8*)(Ks[cur] + (rb * 8 + ((quad + 4) ^ (rb & 7))) * 8);
        s_[j] = __builtin_amdgcn_mfma_f32_16x16x32_bf16(qa[0], kb0, s_[j], 0, 0, 0);
        s_[j] = __builtin_amdgcn_mfma_f32_16x16x32_bf16(qa[1], kb1, s_[j], 0, 0, 0);
      }

      // ---- mask + online softmax (registers) + P write ----
      const int k0 = kt * 128;
      const int rowmin = q0 + wv * 16;
      const int rowb = rowmin + quad * 4;
      if (k0 + 127 > rowmin) {  // diagonal tile: causal mask
        #pragma unroll
        for (int j = 0; j < 8; ++j) {
          const int col = k0 + j * 16 + l15;
          #pragma unroll
          for (int r = 0; r < 4; ++r)
            if (col > rowb + r) s_[j][r] = -3.0e38f;
        }
      }
      float fm[4], al[4], rs[4];
      #pragma unroll
      for (int r = 0; r < 4; ++r) {
        float a = fmaxf(fmaxf(s_[0][r], s_[1][r]), fmaxf(s_[2][r], s_[3][r]));
        float c = fmaxf(fmaxf(s_[4][r], s_[5][r]), fmaxf(s_[6][r], s_[7][r]));
        fm[r] = fmaxf(a, c);
      }
      #pragma unroll
      for (int msk = 1; msk < 16; msk <<= 1)
        #pragma unroll
        for (int r = 0; r < 4; ++r)
          fm[r] = fmaxf(fm[r], __shfl_xor(fm[r], msk, 64));
      #pragma unroll
      for (int r = 0; r < 4; ++r) {
        const float mn = fmaxf(m_i[r], fm[r]);
        al[r] = __expf(m_i[r] - mn);
        m_i[r] = mn;
      }
      #pragma unroll
      for (int j = 0; j < 8; ++j)
        #pragma unroll
        for (int r = 0; r < 4; ++r)
          s_[j][r] = __expf(s_[j][r] - m_i[r]);
      #pragma unroll
      for (int r = 0; r < 4; ++r) {
        float a = (s_[0][r] + s_[1][r]) + (s_[2][r] + s_[3][r]);
        float c = (s_[4][r] + s_[5][r]) + (s_[6][r] + s_[7][r]);
        rs[r] = a + c;
      }
      #pragma unroll
      for (int msk = 1; msk < 16; msk <<= 1)
        #pragma unroll
        for (int r = 0; r < 4; ++r)
          rs[r] += __shfl_xor(rs[r], msk, 64);
      #pragma unroll
      for (int r = 0; r < 4; ++r)
        l_i[r] = l_i[r] * al[r] + rs[r];
      if (l15 == 0) {  // publish alpha (wave-own rows; same-wave read below)
        float4 a4 = { al[0], al[1], al[2], al[3] };
        *(float4*)(stat_s + wv * 16 + quad * 4) = a4;
      }
      #pragma unroll
      for (int j = 0; j < 8; ++j)
        #pragma unroll
        for (int r = 0; r < 4; ++r)
          Ps[(size_t)(wv * 16 + quad * 4 + r) * 136 + j * 16 + l15] = f2bits(s_[j][r]);

      // ---- O^T += V^T P^T (all wave-local LDS; no extra barrier) ----
      const float alq = stat_s[wv * 16 + l15];
      #pragma unroll
      for (int dt = 0; dt < 4; ++dt)
        #pragma unroll
        for (int r = 0; r < 4; ++r)
          oacc[dt][r] *= alq;

      short8 pb[4];
      #pragma unroll
      for (int ks = 0; ks < 4; ++ks)
        pb[ks] = *(const short8*)(Ps + (size_t)(wv * 16 + l15) * 136 + ks * 32 + quad * 8);
      #pragma unroll
      for (int dt = 0; dt < 4; ++dt) {
        short8 va[4];
        #pragma unroll
        for (int ks = 0; ks < 4; ++ks)
          va[ks] = *(const short8*)(VT[cur] + (size_t)(dt * 16 + l15) * 136 + ks * 32 + quad * 8);
        #pragma unroll
        for (int ks = 0; ks < 4; ++ks)
          oacc[dt] = __builtin_amdgcn_mfma_f32_16x16x32_bf16(va[ks], pb[ks], oacc[dt], 0, 0, 0);
      }

      // ---- late write of prefetched V into the other buffer ----
      if (pf) {
        unsigned short* dst = VT[cur ^ 1] + (size_t)(vdc * 8) * 136 + 2 * vp;
        *(unsigned int*)(dst + 0 * 136) = (u0.x & 0xffffu) | (u1.x << 16);
        *(unsigned int*)(dst + 1 * 136) = (u0.x >> 16)     | (u1.x & 0xffff0000u);
        *(unsigned int*)(dst + 2 * 136) = (u0.y & 0xffffu) | (u1.y << 16);
        *(unsigned int*)(dst + 3 * 136) = (u0.y >> 16)     | (u1.y & 0xffff0000u);
        *(unsigned int*)(dst + 4 * 136) = (u0.z & 0xffffu) | (u1.z << 16);
        *(unsigned int*)(dst + 5 * 136) = (u0.z >> 16)     | (u1.z & 0xffff0000u);
        *(unsigned int*)(dst + 6 * 136) = (u0.w & 0xffffu) | (u1.w << 16);
        *(unsigned int*)(dst + 7 * 136) = (u0.w >> 16)     | (u1.w & 0xffff0000u);
      }
      __syncthreads();  // drains next-K DMA (vmcnt) + makes VT[nxt] visible
    }

    // ---- epilogue: O = O^T / l * 32^-1 ----
    if (l15 == 0) {
      float4 l4 = { l_i[0], l_i[1], l_i[2], l_i[3] };
      *(float4*)(stat_s + wv * 16 + quad * 4) = l4;
    }
    const float linv = 0.03125f / stat_s[wv * 16 + l15];
    const size_t row = (size_t)b * 2048 + q0 + wv * 16 + l15;
    #pragma unroll
    for (int dt = 0; dt < 4; ++dt) {
      const int col = h * 64 + dt * 16 + quad * 4;
      ushort4 o4 = { f2bits(oacc[dt][0] * linv), f2bits(oacc[dt][1] * linv),
                     f2bits(oacc[dt][2] * linv), f2bits(oacc[dt][3] * linv) };
      *(ushort4*)(o + row * 1024 + col) = o4;
    }
  }
}

extern "C" void kernel_launch(void* const* d_in, const int* in_sizes, int n_in,
                              void* d_out, int out_size, void* d_ws, size_t ws_size,
                              hipStream_t stream)
{
  (void)in_sizes; (void)n_in; (void)out_size; (void)ws_size;
  const float* x      = (const float*)d_in[0];
  const float* w_attn = (const float*)d_in[1];
  const float* b_attn = (const float*)d_in[2];
  const float* w_proj = (const float*)d_in[3];
  const float* b_proj = (const float*)d_in[4];
  const float* w_fc1  = (const float*)d_in[5];
  const float* b_fc1  = (const float*)d_in[6];
  const float* w_fc2  = (const float*)d_in[7];
  const float* b_fc2  = (const float*)d_in[8];
  const float* g1     = (const float*)d_in[9];
  const float* g2     = (const float*)d_in[10];
  float* out = (float*)d_out;

  // ws layout (88 MB): h/ov bf16 @0 (8MB), qkv bf16 @8MB (24MB, h2 reuses 8..16MB),
  //                    x1 f32 @32MB (16MB), h3 bf16 @48MB (32MB), WT scratch @80MB (8MB)
  // fc2 split-K partials (2 x 16MB f32) reuse 0..32MB (h/h2/qkv/ov all dead there).
  char* ws = (char*)d_ws;
  unsigned short* h   = (unsigned short*)(ws);
  unsigned short* qkv = (unsigned short*)(ws + ((size_t)8  << 20));
  unsigned short* ov  = (unsigned short*)(ws);                       // reuse h
  float*          x1  = (float*)         (ws + ((size_t)32 << 20));
  unsigned short* h2  = (unsigned short*)(ws + ((size_t)8  << 20));  // reuse qkv
  unsigned short* h3  = (unsigned short*)(ws + ((size_t)48 << 20));
  unsigned short* WT  = (unsigned short*)(ws + ((size_t)80 << 20));
  float*          P   = (float*)(ws);                                // fc2 split-K partials

  const int M = 4096;

  rmsnorm_r18<<<M, 256, 0, stream>>>(x, g1, h);
  wprep_r18<<<dim3(3072 / 32, 1024 / 32), 256, 0, stream>>>(w_attn, WT, 1024, 3072);
  gemm256_r18<0><<<dim3(3072 / 256, M / 256), 512, 0, stream>>>(h, WT, b_attn, qkv, M, 3072, 1024);
  attn_r18<<<dim3(8, 32), 512, 0, stream>>>(qkv, ov);
  wprep_r18<<<dim3(1024 / 32, 1024 / 32), 256, 0, stream>>>(w_proj, WT, 1024, 1024);
  gemm128_r18<1><<<dim3(1024 / 128, M / 128), 256, 0, stream>>>(ov, WT, b_proj, x, x1, M, 1024, 1024, 1024);
  rmsnorm_r18<<<M, 256, 0, stream>>>(x1, g2, h2);
  wprep_r18<<<dim3(4096 / 32, 1024 / 32), 256, 0, stream>>>(w_fc1, WT, 1024, 4096);
  gemm256_r18<2><<<dim3(4096 / 256, M / 256), 512, 0, stream>>>(h2, WT, b_fc1, h3, M, 4096, 1024);
  wprep_r18<<<dim3(1024 / 32, 4096 / 32), 256, 0, stream>>>(w_fc2, WT, 4096, 1024);
  gemm128_r18<4><<<dim3(1024 / 128, M / 128, 2), 256, 0, stream>>>(h3, WT, nullptr, nullptr, P, M, 1024, 4096, 2048);
  red2_r18<<<4096, 256, 0, stream>>>(P, x1, b_fc2, out);
}

// Round 11
// 362.727 us; speedup vs baseline: 1.2502x; 1.0200x over previous
//
#include <hip/hip_runtime.h>
#include <hip/hip_bf16.h>

// Transformer block for MI355X. Round 19: catalog levers on r18 (370us best).
//  - T5 setprio(1/0) around MFMA clusters: gemm256 (per-ih phase), gemm128
//    (new 2-phase read grouping), attn (QK and PV loops; waves drift within
//    iter so the hint can arbitrate).
//  - T1 XCD-aware bijective block swizzle on gemm256/gemm128 xy-plane
//    (all grids nwg%8==0; fc2 r1 counters showed 9x HBM overfetch = the
//    HBM-bound regime where swizzle measured +10%).
//  - attn r18 body (KVBLK=128, 17 iters) otherwise unchanged; rmsnorm,
//    wprep, red2 unchanged.
// All symbols _r19 (fresh build).

typedef __hip_bfloat16 bf16;
typedef __attribute__((ext_vector_type(8))) short short8;   // 8 bf16 = 4 VGPRs
typedef __attribute__((ext_vector_type(4))) float floatx4;  // MFMA C/D frag

__device__ __forceinline__ float bits2f(unsigned short u) {
  union { unsigned int i; float f; } c; c.i = ((unsigned int)u) << 16; return c.f;
}
__device__ __forceinline__ unsigned short f2bits(float f) {
  bf16 b = __float2bfloat16(f);
  union { bf16 b; unsigned short u; } c; c.b = b; return c.u;
}

__device__ __forceinline__ void gld_lds16(const unsigned short* g, unsigned short* l) {
  __builtin_amdgcn_global_load_lds(
      (const __attribute__((address_space(1))) void*)g,
      (__attribute__((address_space(3))) void*)l, 16, 0, 0);
}

// XCD-aware bijective swizzle of the xy block index (nwg % 8 == 0 or not).
__device__ __forceinline__ void xcd_swz(int& bx, int& by) {
  const int gx = gridDim.x, nwg = gx * gridDim.y;
  int bid = by * gx + bx;
  const int q = nwg >> 3, r = nwg & 7;
  const int x = bid & 7, yq = bid >> 3;
  int sb = (x < r) ? (x * (q + 1) + yq) : (r * (q + 1) + (x - r) * q + yq);
  bx = sb % gx;
  by = sb / gx;
}

// ---------------- RMSNorm: f32 in, f32 gamma, bf16 out ----------------
__global__ __launch_bounds__(256) void rmsnorm_r19(const float* __restrict__ x,
                                                   const float* __restrict__ g,
                                                   unsigned short* __restrict__ out)
{
  const int row = blockIdx.x, tid = threadIdx.x;
  const size_t rb = (size_t)row * 1024;
  float4 xv = *(const float4*)(x + rb + tid * 4);
  float v[4] = {xv.x, xv.y, xv.z, xv.w};
  float s = v[0]*v[0] + v[1]*v[1] + v[2]*v[2] + v[3]*v[3];
  #pragma unroll
  for (int off = 32; off > 0; off >>= 1) s += __shfl_down(s, off, 64);
  __shared__ float part[4];
  if ((tid & 63) == 0) part[tid >> 6] = s;
  __syncthreads();
  const float tot = part[0] + part[1] + part[2] + part[3];
  const float sc = rsqrtf(tot * (1.0f / 1024.0f) + 1.1920929e-07f);
  float4 gv = *(const float4*)(g + tid * 4);
  ushort4 o4 = { f2bits(v[0] * sc * gv.x), f2bits(v[1] * sc * gv.y),
                 f2bits(v[2] * sc * gv.z), f2bits(v[3] * sc * gv.w) };
  *(ushort4*)(out + rb + tid * 4) = o4;
}

// ---------------- Weight prep: W f32 [K,N] -> WT bf16 [N,K] ----------------
__global__ __launch_bounds__(256) void wprep_r19(const float* __restrict__ in,
                                                 unsigned short* __restrict__ out,
                                                 int K, int N)
{
  __shared__ unsigned short tile[32][33];
  const int tid = threadIdx.x;
  const int k0 = blockIdx.y * 32, n0 = blockIdx.x * 32;
  const int tr = tid >> 3, tc4 = (tid & 7) * 4;
  float4 v = *(const float4*)(in + (size_t)(k0 + tr) * N + n0 + tc4);
  tile[tr][tc4 + 0] = f2bits(v.x);
  tile[tr][tc4 + 1] = f2bits(v.y);
  tile[tr][tc4 + 2] = f2bits(v.z);
  tile[tr][tc4 + 3] = f2bits(v.w);
  __syncthreads();
  ushort4 o = { tile[tc4 + 0][tr], tile[tc4 + 1][tr],
                tile[tc4 + 2][tr], tile[tc4 + 3][tr] };
  *(ushort4*)(out + (size_t)(n0 + tr) * K + k0 + tc4) = o;
}

// ---------------- 128x128 MFMA GEMM (proj / fc2-splitK) ----------------
// EPI: 0=bf16  1=f32+resid  2=gelu->bf16  3=f32+resid  4=f32 partial (split-K)
template<int EPI>
__global__ __launch_bounds__(256) void gemm128_r19(
    const unsigned short* __restrict__ A,
    const unsigned short* __restrict__ BT,
    const float* __restrict__ bias,
    const float* __restrict__ resid,
    void* __restrict__ Cout,
    int M, int N, int K, int Klen)
{
  __shared__ __align__(16) unsigned short As[2][128 * 32];
  __shared__ __align__(16) unsigned short Bs[2][128 * 32];
  const int tid = threadIdx.x;
  const int lane = tid & 63;
  const int wv = tid >> 6;
  int bxs = blockIdx.x, bys = blockIdx.y;
  xcd_swz(bxs, bys);
  const int m0 = bys * 128, n0 = bxs * 128;
  const int wm = (wv >> 1) * 64, wn = (wv & 1) * 64;
  const int kbase = blockIdx.z * Klen;

  const int s0 = tid, s1 = tid + 256;
  const int r0 = s0 >> 2, kq0 = (s0 & 3) ^ ((r0 >> 1) & 3);
  const int r1 = s1 >> 2, kq1 = (s1 & 3) ^ ((r1 >> 1) & 3);
  const unsigned short* Ab = A  + (size_t)m0 * K;
  const unsigned short* Bb = BT + (size_t)n0 * K;
  const size_t ga0 = (size_t)r0 * K + kq0 * 8 + kbase;
  const size_t ga1 = (size_t)r1 * K + kq1 * 8 + kbase;

  floatx4 acc[4][4];
  #pragma unroll
  for (int i = 0; i < 4; ++i)
    #pragma unroll
    for (int j = 0; j < 4; ++j)
      acc[i][j] = (floatx4){0.f, 0.f, 0.f, 0.f};

  int aoff[4], boff[4];
  #pragma unroll
  for (int i = 0; i < 4; ++i) {
    int ra = wm + i * 16 + (lane & 15);
    aoff[i] = (ra * 4 + ((lane >> 4) ^ ((ra >> 1) & 3))) * 8;
    int rb = wn + i * 16 + (lane & 15);
    boff[i] = (rb * 4 + ((lane >> 4) ^ ((rb >> 1) & 3))) * 8;
  }

  gld_lds16(Ab + ga0, As[0] + s0 * 8);
  gld_lds16(Ab + ga1, As[0] + s1 * 8);
  gld_lds16(Bb + ga0, Bs[0] + s0 * 8);
  gld_lds16(Bb + ga1, Bs[0] + s1 * 8);
  __syncthreads();

  const int nsteps = Klen >> 5;
  for (int t = 0; t < nsteps; ++t) {
    const int cur = t & 1;
    if (t + 1 < nsteps) {
      const size_t ko = (size_t)(t + 1) * 32;
      gld_lds16(Ab + ga0 + ko, As[cur ^ 1] + s0 * 8);
      gld_lds16(Ab + ga1 + ko, As[cur ^ 1] + s1 * 8);
      gld_lds16(Bb + ga0 + ko, Bs[cur ^ 1] + s0 * 8);
      gld_lds16(Bb + ga1 + ko, Bs[cur ^ 1] + s1 * 8);
    }

    // phase 0: B frags + A frags 0,1 -> 8 MFMA
    short8 bfr[4], af01[2];
    #pragma unroll
    for (int j = 0; j < 4; ++j)
      bfr[j] = *(const short8*)(Bs[cur] + boff[j]);
    #pragma unroll
    for (int i = 0; i < 2; ++i)
      af01[i] = *(const short8*)(As[cur] + aoff[i]);
    __builtin_amdgcn_s_setprio(1);
    #pragma unroll
    for (int i = 0; i < 2; ++i)
      #pragma unroll
      for (int j = 0; j < 4; ++j)
        acc[i][j] = __builtin_amdgcn_mfma_f32_16x16x32_bf16(af01[i], bfr[j], acc[i][j], 0, 0, 0);
    __builtin_amdgcn_s_setprio(0);
    // phase 1: A frags 2,3 -> 8 MFMA
    short8 af23[2];
    #pragma unroll
    for (int i = 0; i < 2; ++i)
      af23[i] = *(const short8*)(As[cur] + aoff[2 + i]);
    __builtin_amdgcn_s_setprio(1);
    #pragma unroll
    for (int i = 0; i < 2; ++i)
      #pragma unroll
      for (int j = 0; j < 4; ++j)
        acc[2 + i][j] = __builtin_amdgcn_mfma_f32_16x16x32_bf16(af23[i], bfr[j], acc[2 + i][j], 0, 0, 0);
    __builtin_amdgcn_s_setprio(0);

    __syncthreads();
  }

  float* Cp32 = (float*)Cout;
  if constexpr (EPI == 4) Cp32 += (size_t)blockIdx.z * ((size_t)M * N);

  #pragma unroll
  for (int i = 0; i < 4; ++i) {
    #pragma unroll
    for (int j = 0; j < 4; ++j) {
      const int rbase = m0 + wm + i * 16 + (lane >> 4) * 4;
      const int c = n0 + wn + j * 16 + (lane & 15);
      float bia = 0.0f;
      if constexpr (EPI != 4) bia = bias[c];
      #pragma unroll
      for (int r = 0; r < 4; ++r) {
        float v = acc[i][j][r] + bia;
        const size_t idx = (size_t)(rbase + r) * N + c;
        if constexpr (EPI == 0) {
          ((unsigned short*)Cout)[idx] = f2bits(v);
        } else if constexpr (EPI == 1) {
          ((float*)Cout)[idx] = v + resid[idx];
        } else if constexpr (EPI == 2) {
          v = 0.5f * v * (1.0f + erff(v * 0.70710678118654752f));
          ((unsigned short*)Cout)[idx] = f2bits(v);
        } else if constexpr (EPI == 3) {
          ((float*)Cout)[idx] = v + resid[idx];
        } else {
          Cp32[idx] = v;
        }
      }
    }
  }
}

// ---------------- 256x256 MFMA GEMM (qkv / fc1): 4-ring + counted vmcnt + T5 ----------------
template<int EPI>
__global__ __launch_bounds__(512) void gemm256_r19(
    const unsigned short* __restrict__ A,
    const unsigned short* __restrict__ BT,
    const float* __restrict__ bias,
    void* __restrict__ Cout,
    int M, int N, int K)
{
  __shared__ __align__(16) unsigned short As[4][256 * 32];
  __shared__ __align__(16) unsigned short Bs[4][256 * 32];
  const int tid = threadIdx.x;
  const int lane = tid & 63, wv = tid >> 6;
  const int quad = lane >> 4, l15 = lane & 15;
  int bxs = blockIdx.x, bys = blockIdx.y;
  xcd_swz(bxs, bys);
  const int m0 = bys * 256, n0 = bxs * 256;
  const int wm = (wv >> 2) * 128, wn = (wv & 3) * 64;

  const int s0 = tid, s1 = tid + 512;
  const int r0 = s0 >> 2, kq0 = (s0 & 3) ^ ((r0 >> 1) & 3);
  const int r1 = s1 >> 2, kq1 = (s1 & 3) ^ ((r1 >> 1) & 3);
  const unsigned short* Ab = A  + (size_t)m0 * K;
  const unsigned short* Bb = BT + (size_t)n0 * K;
  const size_t ga0 = (size_t)r0 * K + kq0 * 8;
  const size_t ga1 = (size_t)r1 * K + kq1 * 8;

  floatx4 acc[8][4];
  #pragma unroll
  for (int i = 0; i < 8; ++i)
    #pragma unroll
    for (int j = 0; j < 4; ++j)
      acc[i][j] = (floatx4){0.f, 0.f, 0.f, 0.f};

  int aoff[8], boff[4];
  #pragma unroll
  for (int i = 0; i < 8; ++i) {
    int ra = wm + i * 16 + l15;
    aoff[i] = (ra * 4 + (quad ^ ((ra >> 1) & 3))) * 8;
  }
  #pragma unroll
  for (int j = 0; j < 4; ++j) {
    int rb = wn + j * 16 + l15;
    boff[j] = (rb * 4 + (quad ^ ((rb >> 1) & 3))) * 8;
  }

  #define STG_R19(t) { const size_t ko = (size_t)(t) * 32; const int bb = (t) & 3; \
    gld_lds16(Ab + ga0 + ko, As[bb] + s0 * 8); \
    gld_lds16(Ab + ga1 + ko, As[bb] + s1 * 8); \
    gld_lds16(Bb + ga0 + ko, Bs[bb] + s0 * 8); \
    gld_lds16(Bb + ga1 + ko, Bs[bb] + s1 * 8); }

  STG_R19(0);
  STG_R19(1);

  const int nsteps = K >> 5;
  for (int t = 0; t < nsteps; ++t) {
    const int cur = t & 3;
    if (t + 2 < nsteps) {
      STG_R19(t + 2);
      asm volatile("s_waitcnt vmcnt(8)" ::: "memory");
    } else if (t + 1 < nsteps) {
      asm volatile("s_waitcnt vmcnt(4)" ::: "memory");
    } else {
      asm volatile("s_waitcnt vmcnt(0)" ::: "memory");
    }
    __builtin_amdgcn_s_barrier();
    asm volatile("" ::: "memory");

    short8 bfr[4];
    #pragma unroll
    for (int j = 0; j < 4; ++j)
      bfr[j] = *(const short8*)(Bs[cur] + boff[j]);
    #pragma unroll
    for (int ih = 0; ih < 2; ++ih) {
      short8 af[4];
      #pragma unroll
      for (int k = 0; k < 4; ++k)
        af[k] = *(const short8*)(As[cur] + aoff[ih * 4 + k]);
      __builtin_amdgcn_s_setprio(1);
      #pragma unroll
      for (int k = 0; k < 4; ++k)
        #pragma unroll
        for (int j = 0; j < 4; ++j)
          acc[ih * 4 + k][j] = __builtin_amdgcn_mfma_f32_16x16x32_bf16(af[k], bfr[j], acc[ih * 4 + k][j], 0, 0, 0);
      __builtin_amdgcn_s_setprio(0);
    }
  }
  #undef STG_R19

  #pragma unroll
  for (int i = 0; i < 8; ++i) {
    #pragma unroll
    for (int j = 0; j < 4; ++j) {
      const int rbase = m0 + wm + i * 16 + quad * 4;
      const int c = n0 + wn + j * 16 + l15;
      const float bia = bias[c];
      #pragma unroll
      for (int r = 0; r < 4; ++r) {
        float v = acc[i][j][r] + bia;
        const size_t idx = (size_t)(rbase + r) * N + c;
        if constexpr (EPI == 2) {
          v = 0.5f * v * (1.0f + erff(v * 0.70710678118654752f));
        }
        ((unsigned short*)Cout)[idx] = f2bits(v);
      }
    }
  }
}

// ---------------- split-K reduce: out = P0 + P1 + resid + bias ----------------
__global__ __launch_bounds__(256) void red2_r19(const float* __restrict__ P,
                                                const float* __restrict__ resid,
                                                const float* __restrict__ bias,
                                                float* __restrict__ out)
{
  const size_t i = ((size_t)blockIdx.x * 256 + threadIdx.x) * 4;
  const int col = (int)(i & 1023);
  float4 p0 = *(const float4*)(P + i);
  float4 p1 = *(const float4*)(P + ((size_t)4096 * 1024) + i);
  float4 xr = *(const float4*)(resid + i);
  float4 b  = *(const float4*)(bias + col);
  float4 o  = { p0.x + p1.x + xr.x + b.x, p0.y + p1.y + xr.y + b.y,
                p0.z + p1.z + xr.z + b.z, p0.w + p1.w + xr.w + b.w };
  *(float4*)(out + i) = o;
}

// ---------------- MFMA flash attention (r18 body + T5 setprio) ----------------
// KVBLK=128, grid (8,32), 512 threads, qt pair (15-qt0, qt0), 17 iters/block.
__global__ __launch_bounds__(512) void attn_r19(const unsigned short* __restrict__ qkv,
                                                unsigned short* __restrict__ o)
{
  __shared__ __align__(16) unsigned short Qs[128 * 64];
  __shared__ __align__(16) unsigned short Ks[2][128 * 64];
  __shared__ __align__(16) unsigned short VT[2][64 * 136];
  __shared__ __align__(16) unsigned short Ps[128 * 136];
  __shared__ __align__(16) float stat_s[128];

  const int tid = threadIdx.x, lane = tid & 63, wv = tid >> 6;
  const int quad = lane >> 4, l15 = lane & 15;
  const int qt0 = blockIdx.x, bh = blockIdx.y;
  const int b = bh >> 4, h = bh & 15;
  const size_t base = (size_t)b * 2048 * 3072;
  const int qcol = h * 64, kcol = 1024 + h * 64, vcol = 2048 + h * 64;

  const int sr = tid >> 3, scp = tid & 7, sc = scp ^ (sr & 7);
  const unsigned short* kgp = qkv + base + (size_t)sr * 3072 + kcol + sc * 8;
  const int vp = tid & 63, vdc = tid >> 6;
  const unsigned short* vgp = qkv + base + (size_t)(2 * vp) * 3072 + vcol + vdc * 8;

  for (int pass = 0; pass < 2; ++pass) {
    const int qt = pass ? qt0 : 15 - qt0;
    const int q0 = qt * 128;
    const int nkt = qt + 1;

    __syncthreads();

    #pragma unroll
    for (int p = 0; p < 2; ++p) {
      int s = tid + 512 * p;
      int r = s >> 3, cp = s & 7, c = cp ^ (r & 7);
      gld_lds16(qkv + base + (size_t)(q0 + r) * 3072 + qcol + c * 8, Qs + s * 8);
    }
    gld_lds16(kgp, Ks[0] + tid * 8);
    gld_lds16(kgp + (size_t)64 * 3072, Ks[0] + (size_t)(tid + 512) * 8);
    {
      uint4 u0 = *(const uint4*)vgp;
      uint4 u1 = *(const uint4*)(vgp + 3072);
      unsigned short* dst = VT[0] + (size_t)(vdc * 8) * 136 + 2 * vp;
      *(unsigned int*)(dst + 0 * 136) = (u0.x & 0xffffu) | (u1.x << 16);
      *(unsigned int*)(dst + 1 * 136) = (u0.x >> 16)     | (u1.x & 0xffff0000u);
      *(unsigned int*)(dst + 2 * 136) = (u0.y & 0xffffu) | (u1.y << 16);
      *(unsigned int*)(dst + 3 * 136) = (u0.y >> 16)     | (u1.y & 0xffff0000u);
      *(unsigned int*)(dst + 4 * 136) = (u0.z & 0xffffu) | (u1.z << 16);
      *(unsigned int*)(dst + 5 * 136) = (u0.z >> 16)     | (u1.z & 0xffff0000u);
      *(unsigned int*)(dst + 6 * 136) = (u0.w & 0xffffu) | (u1.w << 16);
      *(unsigned int*)(dst + 7 * 136) = (u0.w >> 16)     | (u1.w & 0xffff0000u);
    }
    __syncthreads();

    short8 qa[2];
    #pragma unroll
    for (int ks = 0; ks < 2; ++ks) {
      int ra = wv * 16 + l15;
      int cp = (ks * 4 + quad) ^ (ra & 7);
      qa[ks] = *(const short8*)(Qs + (ra * 8 + cp) * 8);
    }

    floatx4 oacc[4];
    #pragma unroll
    for (int dt = 0; dt < 4; ++dt) oacc[dt] = (floatx4){0.f, 0.f, 0.f, 0.f};
    float m_i[4], l_i[4];
    #pragma unroll
    for (int r = 0; r < 4; ++r) { m_i[r] = -3.0e38f; l_i[r] = 0.0f; }

    for (int kt = 0; kt < nkt; ++kt) {
      const int cur = kt & 1;
      const bool pf = (kt + 1 < nkt);
      uint4 u0, u1;
      if (pf) {
        const size_t koff = (size_t)(kt + 1) * 128 * 3072;
        gld_lds16(kgp + koff, Ks[cur ^ 1] + tid * 8);
        gld_lds16(kgp + koff + (size_t)64 * 3072, Ks[cur ^ 1] + (size_t)(tid + 512) * 8);
        u0 = *(const uint4*)(vgp + koff);
        u1 = *(const uint4*)(vgp + koff + 3072);
      }

      // ---- S = Q K^T over 8 col-tiles ----
      floatx4 s_[8];
      #pragma unroll
      for (int j = 0; j < 8; ++j) s_[j] = (floatx4){0.f, 0.f, 0.f, 0.f};
      __builtin_amdgcn_s_setprio(1);
      #pragma unroll
      for (int j = 0; j < 8; ++j) {
        const int rb = j * 16 + l15;
        short8 kb0 = *(const short8*)(Ks[cur] + (rb * 8 + ((quad    ) ^ (rb & 7))) * 8);
        short8 kb1 = *(const short8*)(Ks[cur] + (rb * 8 + ((quad + 4) ^ (rb & 7))) * 8);
        s_[j] = __builtin_amdgcn_mfma_f32_16x16x32_bf16(qa[0], kb0, s_[j], 0, 0, 0);
        s_[j] = __builtin_amdgcn_mfma_f32_16x16x32_bf16(qa[1], kb1, s_[j], 0, 0, 0);
      }
      __builtin_amdgcn_s_setprio(0);

      // ---- mask + online softmax + P write ----
      const int k0 = kt * 128;
      const int rowmin = q0 + wv * 16;
      const int rowb = rowmin + quad * 4;
      if (k0 + 127 > rowmin) {
        #pragma unroll
        for (int j = 0; j < 8; ++j) {
          const int col = k0 + j * 16 + l15;
          #pragma unroll
          for (int r = 0; r < 4; ++r)
            if (col > rowb + r) s_[j][r] = -3.0e38f;
        }
      }
      float fm[4], al[4], rs[4];
      #pragma unroll
      for (int r = 0; r < 4; ++r) {
        float a = fmaxf(fmaxf(s_[0][r], s_[1][r]), fmaxf(s_[2][r], s_[3][r]));
        float c = fmaxf(fmaxf(s_[4][r], s_[5][r]), fmaxf(s_[6][r], s_[7][r]));
        fm[r] = fmaxf(a, c);
      }
      #pragma unroll
      for (int msk = 1; msk < 16; msk <<= 1)
        #pragma unroll
        for (int r = 0; r < 4; ++r)
          fm[r] = fmaxf(fm[r], __shfl_xor(fm[r], msk, 64));
      #pragma unroll
      for (int r = 0; r < 4; ++r) {
        const float mn = fmaxf(m_i[r], fm[r]);
        al[r] = __expf(m_i[r] - mn);
        m_i[r] = mn;
      }
      #pragma unroll
      for (int j = 0; j < 8; ++j)
        #pragma unroll
        for (int r = 0; r < 4; ++r)
          s_[j][r] = __expf(s_[j][r] - m_i[r]);
      #pragma unroll
      for (int r = 0; r < 4; ++r) {
        float a = (s_[0][r] + s_[1][r]) + (s_[2][r] + s_[3][r]);
        float c = (s_[4][r] + s_[5][r]) + (s_[6][r] + s_[7][r]);
        rs[r] = a + c;
      }
      #pragma unroll
      for (int msk = 1; msk < 16; msk <<= 1)
        #pragma unroll
        for (int r = 0; r < 4; ++r)
          rs[r] += __shfl_xor(rs[r], msk, 64);
      #pragma unroll
      for (int r = 0; r < 4; ++r)
        l_i[r] = l_i[r] * al[r] + rs[r];
      if (l15 == 0) {
        float4 a4 = { al[0], al[1], al[2], al[3] };
        *(float4*)(stat_s + wv * 16 + quad * 4) = a4;
      }
      #pragma unroll
      for (int j = 0; j < 8; ++j)
        #pragma unroll
        for (int r = 0; r < 4; ++r)
          Ps[(size_t)(wv * 16 + quad * 4 + r) * 136 + j * 16 + l15] = f2bits(s_[j][r]);

      // ---- O^T += V^T P^T ----
      const float alq = stat_s[wv * 16 + l15];
      #pragma unroll
      for (int dt = 0; dt < 4; ++dt)
        #pragma unroll
        for (int r = 0; r < 4; ++r)
          oacc[dt][r] *= alq;

      short8 pb[4];
      #pragma unroll
      for (int ks = 0; ks < 4; ++ks)
        pb[ks] = *(const short8*)(Ps + (size_t)(wv * 16 + l15) * 136 + ks * 32 + quad * 8);
      __builtin_amdgcn_s_setprio(1);
      #pragma unroll
      for (int dt = 0; dt < 4; ++dt) {
        short8 va[4];
        #pragma unroll
        for (int ks = 0; ks < 4; ++ks)
          va[ks] = *(const short8*)(VT[cur] + (size_t)(dt * 16 + l15) * 136 + ks * 32 + quad * 8);
        #pragma unroll
        for (int ks = 0; ks < 4; ++ks)
          oacc[dt] = __builtin_amdgcn_mfma_f32_16x16x32_bf16(va[ks], pb[ks], oacc[dt], 0, 0, 0);
      }
      __builtin_amdgcn_s_setprio(0);

      // ---- late write of prefetched V ----
      if (pf) {
        unsigned short* dst = VT[cur ^ 1] + (size_t)(vdc * 8) * 136 + 2 * vp;
        *(unsigned int*)(dst + 0 * 136) = (u0.x & 0xffffu) | (u1.x << 16);
        *(unsigned int*)(dst + 1 * 136) = (u0.x >> 16)     | (u1.x & 0xffff0000u);
        *(unsigned int*)(dst + 2 * 136) = (u0.y & 0xffffu) | (u1.y << 16);
        *(unsigned int*)(dst + 3 * 136) = (u0.y >> 16)     | (u1.y & 0xffff0000u);
        *(unsigned int*)(dst + 4 * 136) = (u0.z & 0xffffu) | (u1.z << 16);
        *(unsigned int*)(dst + 5 * 136) = (u0.z >> 16)     | (u1.z & 0xffff0000u);
        *(unsigned int*)(dst + 6 * 136) = (u0.w & 0xffffu) | (u1.w << 16);
        *(unsigned int*)(dst + 7 * 136) = (u0.w >> 16)     | (u1.w & 0xffff0000u);
      }
      __syncthreads();
    }

    // ---- epilogue: O = O^T / l * 32^-1 ----
    if (l15 == 0) {
      float4 l4 = { l_i[0], l_i[1], l_i[2], l_i[3] };
      *(float4*)(stat_s + wv * 16 + quad * 4) = l4;
    }
    const float linv = 0.03125f / stat_s[wv * 16 + l15];
    const size_t row = (size_t)b * 2048 + q0 + wv * 16 + l15;
    #pragma unroll
    for (int dt = 0; dt < 4; ++dt) {
      const int col = h * 64 + dt * 16 + quad * 4;
      ushort4 o4 = { f2bits(oacc[dt][0] * linv), f2bits(oacc[dt][1] * linv),
                     f2bits(oacc[dt][2] * linv), f2bits(oacc[dt][3] * linv) };
      *(ushort4*)(o + row * 1024 + col) = o4;
    }
  }
}

extern "C" void kernel_launch(void* const* d_in, const int* in_sizes, int n_in,
                              void* d_out, int out_size, void* d_ws, size_t ws_size,
                              hipStream_t stream)
{
  (void)in_sizes; (void)n_in; (void)out_size; (void)ws_size;
  const float* x      = (const float*)d_in[0];
  const float* w_attn = (const float*)d_in[1];
  const float* b_attn = (const float*)d_in[2];
  const float* w_proj = (const float*)d_in[3];
  const float* b_proj = (const float*)d_in[4];
  const float* w_fc1  = (const float*)d_in[5];
  const float* b_fc1  = (const float*)d_in[6];
  const float* w_fc2  = (const float*)d_in[7];
  const float* b_fc2  = (const float*)d_in[8];
  const float* g1     = (const float*)d_in[9];
  const float* g2     = (const float*)d_in[10];
  float* out = (float*)d_out;

  // ws layout (88 MB): h/ov bf16 @0 (8MB), qkv bf16 @8MB (24MB, h2 reuses 8..16MB),
  //                    x1 f32 @32MB (16MB), h3 bf16 @48MB (32MB), WT scratch @80MB (8MB)
  // fc2 split-K partials (2 x 16MB f32) reuse 0..32MB (h/h2/qkv/ov all dead there).
  char* ws = (char*)d_ws;
  unsigned short* h   = (unsigned short*)(ws);
  unsigned short* qkv = (unsigned short*)(ws + ((size_t)8  << 20));
  unsigned short* ov  = (unsigned short*)(ws);                       // reuse h
  float*          x1  = (float*)         (ws + ((size_t)32 << 20));
  unsigned short* h2  = (unsigned short*)(ws + ((size_t)8  << 20));  // reuse qkv
  unsigned short* h3  = (unsigned short*)(ws + ((size_t)48 << 20));
  unsigned short* WT  = (unsigned short*)(ws + ((size_t)80 << 20));
  float*          P   = (float*)(ws);                                // fc2 split-K partials

  const int M = 4096;

  rmsnorm_r19<<<M, 256, 0, stream>>>(x, g1, h);
  wprep_r19<<<dim3(3072 / 32, 1024 / 32), 256, 0, stream>>>(w_attn, WT, 1024, 3072);
  gemm256_r19<0><<<dim3(3072 / 256, M / 256), 512, 0, stream>>>(h, WT, b_attn, qkv, M, 3072, 1024);
  attn_r19<<<dim3(8, 32), 512, 0, stream>>>(qkv, ov);
  wprep_r19<<<dim3(1024 / 32, 1024 / 32), 256, 0, stream>>>(w_proj, WT, 1024, 1024);
  gemm128_r19<1><<<dim3(1024 / 128, M / 128), 256, 0, stream>>>(ov, WT, b_proj, x, x1, M, 1024, 1024, 1024);
  rmsnorm_r19<<<M, 256, 0, stream>>>(x1, g2, h2);
  wprep_r19<<<dim3(4096 / 32, 1024 / 32), 256, 0, stream>>>(w_fc1, WT, 1024, 4096);
  gemm256_r19<2><<<dim3(4096 / 256, M / 256), 512, 0, stream>>>(h2, WT, b_fc1, h3, M, 4096, 1024);
  wprep_r19<<<dim3(1024 / 32, 4096 / 32), 256, 0, stream>>>(w_fc2, WT, 4096, 1024);
  gemm128_r19<4><<<dim3(1024 / 128, M / 128, 2), 256, 0, stream>>>(h3, WT, nullptr, nullptr, P, M, 1024, 4096, 2048);
  red2_r19<<<4096, 256, 0, stream>>>(P, x1, b_fc2, out);
}

// Round 12
// 361.139 us; speedup vs baseline: 1.2557x; 1.0044x over previous
//
#include <hip/hip_runtime.h>
#include <hip/hip_bf16.h>

// Transformer block for MI355X. Round 20: swapped-QK^T attention softmax.
//  - mfma(kb,qa) instead of mfma(qa,kb): same LDS reads, output = S^T with
//    col=q (lane-local q). Row max/sum become in-register trees + TWO
//    shfl_xor steps (was 2x 4-step chains); m/l/alpha lane-local scalars
//    (stat_s deleted); P written as 8 packed ds_write_b64 (was 32 u16).
//    PV fragments and O^T epilogue already match - unchanged.
//  - attn setprio removed (r19: -1us on attn, lockstep null per m190).
//  - gemm256/gemm128 (T1 swizzle + T5 phases), rmsnorm, wprep, red2
//    unchanged from r19 (362.7us best).
// All symbols _r20 (fresh build).

typedef __hip_bfloat16 bf16;
typedef __attribute__((ext_vector_type(8))) short short8;   // 8 bf16 = 4 VGPRs
typedef __attribute__((ext_vector_type(4))) float floatx4;  // MFMA C/D frag

__device__ __forceinline__ float bits2f(unsigned short u) {
  union { unsigned int i; float f; } c; c.i = ((unsigned int)u) << 16; return c.f;
}
__device__ __forceinline__ unsigned short f2bits(float f) {
  bf16 b = __float2bfloat16(f);
  union { bf16 b; unsigned short u; } c; c.b = b; return c.u;
}

__device__ __forceinline__ void gld_lds16(const unsigned short* g, unsigned short* l) {
  __builtin_amdgcn_global_load_lds(
      (const __attribute__((address_space(1))) void*)g,
      (__attribute__((address_space(3))) void*)l, 16, 0, 0);
}

// XCD-aware bijective swizzle of the xy block index.
__device__ __forceinline__ void xcd_swz(int& bx, int& by) {
  const int gx = gridDim.x, nwg = gx * gridDim.y;
  int bid = by * gx + bx;
  const int q = nwg >> 3, r = nwg & 7;
  const int x = bid & 7, yq = bid >> 3;
  int sb = (x < r) ? (x * (q + 1) + yq) : (r * (q + 1) + (x - r) * q + yq);
  bx = sb % gx;
  by = sb / gx;
}

// ---------------- RMSNorm: f32 in, f32 gamma, bf16 out ----------------
__global__ __launch_bounds__(256) void rmsnorm_r20(const float* __restrict__ x,
                                                   const float* __restrict__ g,
                                                   unsigned short* __restrict__ out)
{
  const int row = blockIdx.x, tid = threadIdx.x;
  const size_t rb = (size_t)row * 1024;
  float4 xv = *(const float4*)(x + rb + tid * 4);
  float v[4] = {xv.x, xv.y, xv.z, xv.w};
  float s = v[0]*v[0] + v[1]*v[1] + v[2]*v[2] + v[3]*v[3];
  #pragma unroll
  for (int off = 32; off > 0; off >>= 1) s += __shfl_down(s, off, 64);
  __shared__ float part[4];
  if ((tid & 63) == 0) part[tid >> 6] = s;
  __syncthreads();
  const float tot = part[0] + part[1] + part[2] + part[3];
  const float sc = rsqrtf(tot * (1.0f / 1024.0f) + 1.1920929e-07f);
  float4 gv = *(const float4*)(g + tid * 4);
  ushort4 o4 = { f2bits(v[0] * sc * gv.x), f2bits(v[1] * sc * gv.y),
                 f2bits(v[2] * sc * gv.z), f2bits(v[3] * sc * gv.w) };
  *(ushort4*)(out + rb + tid * 4) = o4;
}

// ---------------- Weight prep: W f32 [K,N] -> WT bf16 [N,K] ----------------
__global__ __launch_bounds__(256) void wprep_r20(const float* __restrict__ in,
                                                 unsigned short* __restrict__ out,
                                                 int K, int N)
{
  __shared__ unsigned short tile[32][33];
  const int tid = threadIdx.x;
  const int k0 = blockIdx.y * 32, n0 = blockIdx.x * 32;
  const int tr = tid >> 3, tc4 = (tid & 7) * 4;
  float4 v = *(const float4*)(in + (size_t)(k0 + tr) * N + n0 + tc4);
  tile[tr][tc4 + 0] = f2bits(v.x);
  tile[tr][tc4 + 1] = f2bits(v.y);
  tile[tr][tc4 + 2] = f2bits(v.z);
  tile[tr][tc4 + 3] = f2bits(v.w);
  __syncthreads();
  ushort4 o = { tile[tc4 + 0][tr], tile[tc4 + 1][tr],
                tile[tc4 + 2][tr], tile[tc4 + 3][tr] };
  *(ushort4*)(out + (size_t)(n0 + tr) * K + k0 + tc4) = o;
}

// ---------------- 128x128 MFMA GEMM (proj / fc2-splitK) ----------------
// EPI: 0=bf16  1=f32+resid  2=gelu->bf16  3=f32+resid  4=f32 partial (split-K)
template<int EPI>
__global__ __launch_bounds__(256) void gemm128_r20(
    const unsigned short* __restrict__ A,
    const unsigned short* __restrict__ BT,
    const float* __restrict__ bias,
    const float* __restrict__ resid,
    void* __restrict__ Cout,
    int M, int N, int K, int Klen)
{
  __shared__ __align__(16) unsigned short As[2][128 * 32];
  __shared__ __align__(16) unsigned short Bs[2][128 * 32];
  const int tid = threadIdx.x;
  const int lane = tid & 63;
  const int wv = tid >> 6;
  int bxs = blockIdx.x, bys = blockIdx.y;
  xcd_swz(bxs, bys);
  const int m0 = bys * 128, n0 = bxs * 128;
  const int wm = (wv >> 1) * 64, wn = (wv & 1) * 64;
  const int kbase = blockIdx.z * Klen;

  const int s0 = tid, s1 = tid + 256;
  const int r0 = s0 >> 2, kq0 = (s0 & 3) ^ ((r0 >> 1) & 3);
  const int r1 = s1 >> 2, kq1 = (s1 & 3) ^ ((r1 >> 1) & 3);
  const unsigned short* Ab = A  + (size_t)m0 * K;
  const unsigned short* Bb = BT + (size_t)n0 * K;
  const size_t ga0 = (size_t)r0 * K + kq0 * 8 + kbase;
  const size_t ga1 = (size_t)r1 * K + kq1 * 8 + kbase;

  floatx4 acc[4][4];
  #pragma unroll
  for (int i = 0; i < 4; ++i)
    #pragma unroll
    for (int j = 0; j < 4; ++j)
      acc[i][j] = (floatx4){0.f, 0.f, 0.f, 0.f};

  int aoff[4], boff[4];
  #pragma unroll
  for (int i = 0; i < 4; ++i) {
    int ra = wm + i * 16 + (lane & 15);
    aoff[i] = (ra * 4 + ((lane >> 4) ^ ((ra >> 1) & 3))) * 8;
    int rb = wn + i * 16 + (lane & 15);
    boff[i] = (rb * 4 + ((lane >> 4) ^ ((rb >> 1) & 3))) * 8;
  }

  gld_lds16(Ab + ga0, As[0] + s0 * 8);
  gld_lds16(Ab + ga1, As[0] + s1 * 8);
  gld_lds16(Bb + ga0, Bs[0] + s0 * 8);
  gld_lds16(Bb + ga1, Bs[0] + s1 * 8);
  __syncthreads();

  const int nsteps = Klen >> 5;
  for (int t = 0; t < nsteps; ++t) {
    const int cur = t & 1;
    if (t + 1 < nsteps) {
      const size_t ko = (size_t)(t + 1) * 32;
      gld_lds16(Ab + ga0 + ko, As[cur ^ 1] + s0 * 8);
      gld_lds16(Ab + ga1 + ko, As[cur ^ 1] + s1 * 8);
      gld_lds16(Bb + ga0 + ko, Bs[cur ^ 1] + s0 * 8);
      gld_lds16(Bb + ga1 + ko, Bs[cur ^ 1] + s1 * 8);
    }

    short8 bfr[4], af01[2];
    #pragma unroll
    for (int j = 0; j < 4; ++j)
      bfr[j] = *(const short8*)(Bs[cur] + boff[j]);
    #pragma unroll
    for (int i = 0; i < 2; ++i)
      af01[i] = *(const short8*)(As[cur] + aoff[i]);
    __builtin_amdgcn_s_setprio(1);
    #pragma unroll
    for (int i = 0; i < 2; ++i)
      #pragma unroll
      for (int j = 0; j < 4; ++j)
        acc[i][j] = __builtin_amdgcn_mfma_f32_16x16x32_bf16(af01[i], bfr[j], acc[i][j], 0, 0, 0);
    __builtin_amdgcn_s_setprio(0);
    short8 af23[2];
    #pragma unroll
    for (int i = 0; i < 2; ++i)
      af23[i] = *(const short8*)(As[cur] + aoff[2 + i]);
    __builtin_amdgcn_s_setprio(1);
    #pragma unroll
    for (int i = 0; i < 2; ++i)
      #pragma unroll
      for (int j = 0; j < 4; ++j)
        acc[2 + i][j] = __builtin_amdgcn_mfma_f32_16x16x32_bf16(af23[i], bfr[j], acc[2 + i][j], 0, 0, 0);
    __builtin_amdgcn_s_setprio(0);

    __syncthreads();
  }

  float* Cp32 = (float*)Cout;
  if constexpr (EPI == 4) Cp32 += (size_t)blockIdx.z * ((size_t)M * N);

  #pragma unroll
  for (int i = 0; i < 4; ++i) {
    #pragma unroll
    for (int j = 0; j < 4; ++j) {
      const int rbase = m0 + wm + i * 16 + (lane >> 4) * 4;
      const int c = n0 + wn + j * 16 + (lane & 15);
      float bia = 0.0f;
      if constexpr (EPI != 4) bia = bias[c];
      #pragma unroll
      for (int r = 0; r < 4; ++r) {
        float v = acc[i][j][r] + bia;
        const size_t idx = (size_t)(rbase + r) * N + c;
        if constexpr (EPI == 0) {
          ((unsigned short*)Cout)[idx] = f2bits(v);
        } else if constexpr (EPI == 1) {
          ((float*)Cout)[idx] = v + resid[idx];
        } else if constexpr (EPI == 2) {
          v = 0.5f * v * (1.0f + erff(v * 0.70710678118654752f));
          ((unsigned short*)Cout)[idx] = f2bits(v);
        } else if constexpr (EPI == 3) {
          ((float*)Cout)[idx] = v + resid[idx];
        } else {
          Cp32[idx] = v;
        }
      }
    }
  }
}

// ---------------- 256x256 MFMA GEMM (qkv / fc1): 4-ring + counted vmcnt + T5 ----------------
template<int EPI>
__global__ __launch_bounds__(512) void gemm256_r20(
    const unsigned short* __restrict__ A,
    const unsigned short* __restrict__ BT,
    const float* __restrict__ bias,
    void* __restrict__ Cout,
    int M, int N, int K)
{
  __shared__ __align__(16) unsigned short As[4][256 * 32];
  __shared__ __align__(16) unsigned short Bs[4][256 * 32];
  const int tid = threadIdx.x;
  const int lane = tid & 63, wv = tid >> 6;
  const int quad = lane >> 4, l15 = lane & 15;
  int bxs = blockIdx.x, bys = blockIdx.y;
  xcd_swz(bxs, bys);
  const int m0 = bys * 256, n0 = bxs * 256;
  const int wm = (wv >> 2) * 128, wn = (wv & 3) * 64;

  const int s0 = tid, s1 = tid + 512;
  const int r0 = s0 >> 2, kq0 = (s0 & 3) ^ ((r0 >> 1) & 3);
  const int r1 = s1 >> 2, kq1 = (s1 & 3) ^ ((r1 >> 1) & 3);
  const unsigned short* Ab = A  + (size_t)m0 * K;
  const unsigned short* Bb = BT + (size_t)n0 * K;
  const size_t ga0 = (size_t)r0 * K + kq0 * 8;
  const size_t ga1 = (size_t)r1 * K + kq1 * 8;

  floatx4 acc[8][4];
  #pragma unroll
  for (int i = 0; i < 8; ++i)
    #pragma unroll
    for (int j = 0; j < 4; ++j)
      acc[i][j] = (floatx4){0.f, 0.f, 0.f, 0.f};

  int aoff[8], boff[4];
  #pragma unroll
  for (int i = 0; i < 8; ++i) {
    int ra = wm + i * 16 + l15;
    aoff[i] = (ra * 4 + (quad ^ ((ra >> 1) & 3))) * 8;
  }
  #pragma unroll
  for (int j = 0; j < 4; ++j) {
    int rb = wn + j * 16 + l15;
    boff[j] = (rb * 4 + (quad ^ ((rb >> 1) & 3))) * 8;
  }

  #define STG_R20(t) { const size_t ko = (size_t)(t) * 32; const int bb = (t) & 3; \
    gld_lds16(Ab + ga0 + ko, As[bb] + s0 * 8); \
    gld_lds16(Ab + ga1 + ko, As[bb] + s1 * 8); \
    gld_lds16(Bb + ga0 + ko, Bs[bb] + s0 * 8); \
    gld_lds16(Bb + ga1 + ko, Bs[bb] + s1 * 8); }

  STG_R20(0);
  STG_R20(1);

  const int nsteps = K >> 5;
  for (int t = 0; t < nsteps; ++t) {
    const int cur = t & 3;
    if (t + 2 < nsteps) {
      STG_R20(t + 2);
      asm volatile("s_waitcnt vmcnt(8)" ::: "memory");
    } else if (t + 1 < nsteps) {
      asm volatile("s_waitcnt vmcnt(4)" ::: "memory");
    } else {
      asm volatile("s_waitcnt vmcnt(0)" ::: "memory");
    }
    __builtin_amdgcn_s_barrier();
    asm volatile("" ::: "memory");

    short8 bfr[4];
    #pragma unroll
    for (int j = 0; j < 4; ++j)
      bfr[j] = *(const short8*)(Bs[cur] + boff[j]);
    #pragma unroll
    for (int ih = 0; ih < 2; ++ih) {
      short8 af[4];
      #pragma unroll
      for (int k = 0; k < 4; ++k)
        af[k] = *(const short8*)(As[cur] + aoff[ih * 4 + k]);
      __builtin_amdgcn_s_setprio(1);
      #pragma unroll
      for (int k = 0; k < 4; ++k)
        #pragma unroll
        for (int j = 0; j < 4; ++j)
          acc[ih * 4 + k][j] = __builtin_amdgcn_mfma_f32_16x16x32_bf16(af[k], bfr[j], acc[ih * 4 + k][j], 0, 0, 0);
      __builtin_amdgcn_s_setprio(0);
    }
  }
  #undef STG_R20

  #pragma unroll
  for (int i = 0; i < 8; ++i) {
    #pragma unroll
    for (int j = 0; j < 4; ++j) {
      const int rbase = m0 + wm + i * 16 + quad * 4;
      const int c = n0 + wn + j * 16 + l15;
      const float bia = bias[c];
      #pragma unroll
      for (int r = 0; r < 4; ++r) {
        float v = acc[i][j][r] + bia;
        const size_t idx = (size_t)(rbase + r) * N + c;
        if constexpr (EPI == 2) {
          v = 0.5f * v * (1.0f + erff(v * 0.70710678118654752f));
        }
        ((unsigned short*)Cout)[idx] = f2bits(v);
      }
    }
  }
}

// ---------------- split-K reduce: out = P0 + P1 + resid + bias ----------------
__global__ __launch_bounds__(256) void red2_r20(const float* __restrict__ P,
                                                const float* __restrict__ resid,
                                                const float* __restrict__ bias,
                                                float* __restrict__ out)
{
  const size_t i = ((size_t)blockIdx.x * 256 + threadIdx.x) * 4;
  const int col = (int)(i & 1023);
  float4 p0 = *(const float4*)(P + i);
  float4 p1 = *(const float4*)(P + ((size_t)4096 * 1024) + i);
  float4 xr = *(const float4*)(resid + i);
  float4 b  = *(const float4*)(bias + col);
  float4 o  = { p0.x + p1.x + xr.x + b.x, p0.y + p1.y + xr.y + b.y,
                p0.z + p1.z + xr.z + b.z, p0.w + p1.w + xr.w + b.w };
  *(float4*)(out + i) = o;
}

// ---------------- MFMA flash attention (r20: swapped QK^T, lane-local softmax) ----------------
// KVBLK=128, grid (8,32), 512 threads, qt pair (15-qt0, qt0), 17 iters/block.
// s_ = S^T (col=q=l15, row=tok=quad*4+r): mfma(kb,qa). Softmax per-lane scalar
// m/l; reduce = in-reg tree + shfl_xor(16) + shfl_xor(32). P packed b64 writes.
__global__ __launch_bounds__(512) void attn_r20(const unsigned short* __restrict__ qkv,
                                                unsigned short* __restrict__ o)
{
  __shared__ __align__(16) unsigned short Qs[128 * 64];
  __shared__ __align__(16) unsigned short Ks[2][128 * 64];
  __shared__ __align__(16) unsigned short VT[2][64 * 136];
  __shared__ __align__(16) unsigned short Ps[128 * 136];

  const int tid = threadIdx.x, lane = tid & 63, wv = tid >> 6;
  const int quad = lane >> 4, l15 = lane & 15;
  const int qt0 = blockIdx.x, bh = blockIdx.y;
  const int b = bh >> 4, h = bh & 15;
  const size_t base = (size_t)b * 2048 * 3072;
  const int qcol = h * 64, kcol = 1024 + h * 64, vcol = 2048 + h * 64;

  const int sr = tid >> 3, scp = tid & 7, sc = scp ^ (sr & 7);
  const unsigned short* kgp = qkv + base + (size_t)sr * 3072 + kcol + sc * 8;
  const int vp = tid & 63, vdc = tid >> 6;
  const unsigned short* vgp = qkv + base + (size_t)(2 * vp) * 3072 + vcol + vdc * 8;

  for (int pass = 0; pass < 2; ++pass) {
    const int qt = pass ? qt0 : 15 - qt0;
    const int q0 = qt * 128;
    const int nkt = qt + 1;

    __syncthreads();

    #pragma unroll
    for (int p = 0; p < 2; ++p) {
      int s = tid + 512 * p;
      int r = s >> 3, cp = s & 7, c = cp ^ (r & 7);
      gld_lds16(qkv + base + (size_t)(q0 + r) * 3072 + qcol + c * 8, Qs + s * 8);
    }
    gld_lds16(kgp, Ks[0] + tid * 8);
    gld_lds16(kgp + (size_t)64 * 3072, Ks[0] + (size_t)(tid + 512) * 8);
    {
      uint4 u0 = *(const uint4*)vgp;
      uint4 u1 = *(const uint4*)(vgp + 3072);
      unsigned short* dst = VT[0] + (size_t)(vdc * 8) * 136 + 2 * vp;
      *(unsigned int*)(dst + 0 * 136) = (u0.x & 0xffffu) | (u1.x << 16);
      *(unsigned int*)(dst + 1 * 136) = (u0.x >> 16)     | (u1.x & 0xffff0000u);
      *(unsigned int*)(dst + 2 * 136) = (u0.y & 0xffffu) | (u1.y << 16);
      *(unsigned int*)(dst + 3 * 136) = (u0.y >> 16)     | (u1.y & 0xffff0000u);
      *(unsigned int*)(dst + 4 * 136) = (u0.z & 0xffffu) | (u1.z << 16);
      *(unsigned int*)(dst + 5 * 136) = (u0.z >> 16)     | (u1.z & 0xffff0000u);
      *(unsigned int*)(dst + 6 * 136) = (u0.w & 0xffffu) | (u1.w << 16);
      *(unsigned int*)(dst + 7 * 136) = (u0.w >> 16)     | (u1.w & 0xffff0000u);
    }
    __syncthreads();

    short8 qa[2];
    #pragma unroll
    for (int ks = 0; ks < 2; ++ks) {
      int ra = wv * 16 + l15;
      int cp = (ks * 4 + quad) ^ (ra & 7);
      qa[ks] = *(const short8*)(Qs + (ra * 8 + cp) * 8);
    }

    floatx4 oacc[4];
    #pragma unroll
    for (int dt = 0; dt < 4; ++dt) oacc[dt] = (floatx4){0.f, 0.f, 0.f, 0.f};
    float m_i = -3.0e38f, l_i = 0.0f;

    for (int kt = 0; kt < nkt; ++kt) {
      const int cur = kt & 1;
      const bool pf = (kt + 1 < nkt);
      uint4 u0, u1;
      if (pf) {
        const size_t koff = (size_t)(kt + 1) * 128 * 3072;
        gld_lds16(kgp + koff, Ks[cur ^ 1] + tid * 8);
        gld_lds16(kgp + koff + (size_t)64 * 3072, Ks[cur ^ 1] + (size_t)(tid + 512) * 8);
        u0 = *(const uint4*)(vgp + koff);
        u1 = *(const uint4*)(vgp + koff + 3072);
      }

      // ---- S^T = K Q^T over 8 tok-tiles (swapped operands; same LDS reads) ----
      floatx4 s_[8];
      #pragma unroll
      for (int j = 0; j < 8; ++j) s_[j] = (floatx4){0.f, 0.f, 0.f, 0.f};
      #pragma unroll
      for (int j = 0; j < 8; ++j) {
        const int rb = j * 16 + l15;
        short8 kb0 = *(const short8*)(Ks[cur] + (rb * 8 + ((quad    ) ^ (rb & 7))) * 8);
        short8 kb1 = *(const short8*)(Ks[cur] + (rb * 8 + ((quad + 4) ^ (rb & 7))) * 8);
        s_[j] = __builtin_amdgcn_mfma_f32_16x16x32_bf16(kb0, qa[0], s_[j], 0, 0, 0);
        s_[j] = __builtin_amdgcn_mfma_f32_16x16x32_bf16(kb1, qa[1], s_[j], 0, 0, 0);
      }

      // ---- mask + lane-local online softmax ----
      const int k0 = kt * 128;
      const int qg = q0 + wv * 16 + l15;          // this lane's q (all its s_ cols)
      if (k0 + 127 > q0 + wv * 16) {              // boundary tile: causal mask
        #pragma unroll
        for (int j = 0; j < 8; ++j) {
          const int tokb = k0 + j * 16 + quad * 4;
          #pragma unroll
          for (int r = 0; r < 4; ++r)
            if (tokb + r > qg) s_[j][r] = -3.0e38f;
        }
      }
      // max over this lane's 32 tok values (tree), then 2 shfl_xor steps
      float t8m[8];
      #pragma unroll
      for (int j = 0; j < 8; ++j)
        t8m[j] = fmaxf(fmaxf(s_[j][0], s_[j][1]), fmaxf(s_[j][2], s_[j][3]));
      float pmax = fmaxf(fmaxf(fmaxf(t8m[0], t8m[1]), fmaxf(t8m[2], t8m[3])),
                         fmaxf(fmaxf(t8m[4], t8m[5]), fmaxf(t8m[6], t8m[7])));
      pmax = fmaxf(pmax, __shfl_xor(pmax, 16, 64));
      pmax = fmaxf(pmax, __shfl_xor(pmax, 32, 64));
      const float mn = fmaxf(m_i, pmax);
      const float al = __expf(m_i - mn);
      m_i = mn;
      #pragma unroll
      for (int j = 0; j < 8; ++j)
        #pragma unroll
        for (int r = 0; r < 4; ++r)
          s_[j][r] = __expf(s_[j][r] - mn);
      float t8s[8];
      #pragma unroll
      for (int j = 0; j < 8; ++j)
        t8s[j] = (s_[j][0] + s_[j][1]) + (s_[j][2] + s_[j][3]);
      float rs = ((t8s[0] + t8s[1]) + (t8s[2] + t8s[3])) +
                 ((t8s[4] + t8s[5]) + (t8s[6] + t8s[7]));
      rs += __shfl_xor(rs, 16, 64);
      rs += __shfl_xor(rs, 32, 64);
      l_i = l_i * al + rs;

      // ---- P write: packed b64, Ps[q][tok] (lane: 4 consecutive tok per j) ----
      {
        unsigned short* prow = Ps + (size_t)(wv * 16 + l15) * 136 + quad * 4;
        #pragma unroll
        for (int j = 0; j < 8; ++j) {
          unsigned long long pk =
              (unsigned long long)f2bits(s_[j][0])
            | ((unsigned long long)f2bits(s_[j][1]) << 16)
            | ((unsigned long long)f2bits(s_[j][2]) << 32)
            | ((unsigned long long)f2bits(s_[j][3]) << 48);
          *(unsigned long long*)(prow + j * 16) = pk;
        }
      }

      // ---- O^T += V^T P^T (lane-local alpha rescale) ----
      #pragma unroll
      for (int dt = 0; dt < 4; ++dt)
        #pragma unroll
        for (int r = 0; r < 4; ++r)
          oacc[dt][r] *= al;

      short8 pb[4];
      #pragma unroll
      for (int ks = 0; ks < 4; ++ks)
        pb[ks] = *(const short8*)(Ps + (size_t)(wv * 16 + l15) * 136 + ks * 32 + quad * 8);
      #pragma unroll
      for (int dt = 0; dt < 4; ++dt) {
        short8 va[4];
        #pragma unroll
        for (int ks = 0; ks < 4; ++ks)
          va[ks] = *(const short8*)(VT[cur] + (size_t)(dt * 16 + l15) * 136 + ks * 32 + quad * 8);
        #pragma unroll
        for (int ks = 0; ks < 4; ++ks)
          oacc[dt] = __builtin_amdgcn_mfma_f32_16x16x32_bf16(va[ks], pb[ks], oacc[dt], 0, 0, 0);
      }

      // ---- late write of prefetched V ----
      if (pf) {
        unsigned short* dst = VT[cur ^ 1] + (size_t)(vdc * 8) * 136 + 2 * vp;
        *(unsigned int*)(dst + 0 * 136) = (u0.x & 0xffffu) | (u1.x << 16);
        *(unsigned int*)(dst + 1 * 136) = (u0.x >> 16)     | (u1.x & 0xffff0000u);
        *(unsigned int*)(dst + 2 * 136) = (u0.y & 0xffffu) | (u1.y << 16);
        *(unsigned int*)(dst + 3 * 136) = (u0.y >> 16)     | (u1.y & 0xffff0000u);
        *(unsigned int*)(dst + 4 * 136) = (u0.z & 0xffffu) | (u1.z << 16);
        *(unsigned int*)(dst + 5 * 136) = (u0.z >> 16)     | (u1.z & 0xffff0000u);
        *(unsigned int*)(dst + 6 * 136) = (u0.w & 0xffffu) | (u1.w << 16);
        *(unsigned int*)(dst + 7 * 136) = (u0.w >> 16)     | (u1.w & 0xffff0000u);
      }
      __syncthreads();
    }

    // ---- epilogue: O = O^T / l * 32^-1 (l lane-local) ----
    const float linv = 0.03125f / l_i;
    const size_t row = (size_t)b * 2048 + q0 + wv * 16 + l15;
    #pragma unroll
    for (int dt = 0; dt < 4; ++dt) {
      const int col = h * 64 + dt * 16 + quad * 4;
      ushort4 o4 = { f2bits(oacc[dt][0] * linv), f2bits(oacc[dt][1] * linv),
                     f2bits(oacc[dt][2] * linv), f2bits(oacc[dt][3] * linv) };
      *(ushort4*)(o + row * 1024 + col) = o4;
    }
  }
}

extern "C" void kernel_launch(void* const* d_in, const int* in_sizes, int n_in,
                              void* d_out, int out_size, void* d_ws, size_t ws_size,
                              hipStream_t stream)
{
  (void)in_sizes; (void)n_in; (void)out_size; (void)ws_size;
  const float* x      = (const float*)d_in[0];
  const float* w_attn = (const float*)d_in[1];
  const float* b_attn = (const float*)d_in[2];
  const float* w_proj = (const float*)d_in[3];
  const float* b_proj = (const float*)d_in[4];
  const float* w_fc1  = (const float*)d_in[5];
  const float* b_fc1  = (const float*)d_in[6];
  const float* w_fc2  = (const float*)d_in[7];
  const float* b_fc2  = (const float*)d_in[8];
  const float* g1     = (const float*)d_in[9];
  const float* g2     = (const float*)d_in[10];
  float* out = (float*)d_out;

  // ws layout (88 MB): h/ov bf16 @0 (8MB), qkv bf16 @8MB (24MB, h2 reuses 8..16MB),
  //                    x1 f32 @32MB (16MB), h3 bf16 @48MB (32MB), WT scratch @80MB (8MB)
  // fc2 split-K partials (2 x 16MB f32) reuse 0..32MB (h/h2/qkv/ov all dead there).
  char* ws = (char*)d_ws;
  unsigned short* h   = (unsigned short*)(ws);
  unsigned short* qkv = (unsigned short*)(ws + ((size_t)8  << 20));
  unsigned short* ov  = (unsigned short*)(ws);                       // reuse h
  float*          x1  = (float*)         (ws + ((size_t)32 << 20));
  unsigned short* h2  = (unsigned short*)(ws + ((size_t)8  << 20));  // reuse qkv
  unsigned short* h3  = (unsigned short*)(ws + ((size_t)48 << 20));
  unsigned short* WT  = (unsigned short*)(ws + ((size_t)80 << 20));
  float*          P   = (float*)(ws);                                // fc2 split-K partials

  const int M = 4096;

  rmsnorm_r20<<<M, 256, 0, stream>>>(x, g1, h);
  wprep_r20<<<dim3(3072 / 32, 1024 / 32), 256, 0, stream>>>(w_attn, WT, 1024, 3072);
  gemm256_r20<0><<<dim3(3072 / 256, M / 256), 512, 0, stream>>>(h, WT, b_attn, qkv, M, 3072, 1024);
  attn_r20<<<dim3(8, 32), 512, 0, stream>>>(qkv, ov);
  wprep_r20<<<dim3(1024 / 32, 1024 / 32), 256, 0, stream>>>(w_proj, WT, 1024, 1024);
  gemm128_r20<1><<<dim3(1024 / 128, M / 128), 256, 0, stream>>>(ov, WT, b_proj, x, x1, M, 1024, 1024, 1024);
  rmsnorm_r20<<<M, 256, 0, stream>>>(x1, g2, h2);
  wprep_r20<<<dim3(4096 / 32, 1024 / 32), 256, 0, stream>>>(w_fc1, WT, 1024, 4096);
  gemm256_r20<2><<<dim3(4096 / 256, M / 256), 512, 0, stream>>>(h2, WT, b_fc1, h3, M, 4096, 1024);
  wprep_r20<<<dim3(1024 / 32, 4096 / 32), 256, 0, stream>>>(w_fc2, WT, 4096, 1024);
  gemm128_r20<4><<<dim3(1024 / 128, M / 128, 2), 256, 0, stream>>>(h3, WT, nullptr, nullptr, P, M, 1024, 4096, 2048);
  red2_r20<<<4096, 256, 0, stream>>>(P, x1, b_fc2, out);
}